// Round 14
// baseline (1439.518 us; speedup 1.0000x reference)
//
#include <hip/hip_runtime.h>
#include <hip/hip_bf16.h>
#include <math.h>

#define B_ 128
#define L_ 196
#define D_ 512
#define T_ 20
#define V_ 10000
#define E_ 256
#define H_ 512
#define A_ 512
#define TM1 19
#define ROWS (TM1*B_)      /* 2432 */
#define G4H 2048
#define KCAT 1024
#define LH 98

typedef unsigned short ushort_t;
typedef __attribute__((ext_vector_type(8))) short bf16x8;
typedef __attribute__((ext_vector_type(4))) float f32x4;

__device__ __forceinline__ float fast_tanh(float x){
    float ax = fabsf(x);
    float e = __expf(-2.f*ax);
    float r = __builtin_amdgcn_rcpf(1.f + e);
    return copysignf((1.f - e)*r, x);
}
__device__ __forceinline__ float sigmoidf_(float x){
    return __builtin_amdgcn_rcpf(1.f + __expf(-x));
}
__device__ __forceinline__ ushort_t f2b(float f){
    union{float f; unsigned u;} x; x.f = f;
    unsigned r = x.u + 0x7fffu + ((x.u>>16)&1u);
    return (ushort_t)(r>>16);
}
__device__ __forceinline__ float b2f(ushort_t h){
    union{unsigned u; float f;} x; x.u = ((unsigned)h)<<16;
    return x.f;
}
__device__ __forceinline__ float b2f_lo(unsigned u){ union{unsigned u; float f;} x; x.u = u<<16; return x.f; }
__device__ __forceinline__ float b2f_hi(unsigned u){ union{unsigned u; float f;} x; x.u = u & 0xffff0000u; return x.f; }

#define GL16(gsrc, ldst) __builtin_amdgcn_global_load_lds( \
    (const __attribute__((address_space(1))) unsigned*)(gsrc), \
    (__attribute__((address_space(3))) unsigned*)(ldst), 16, 0, 0)

// ================= logits GEMM (template, SWZ path): dbuf global_load_lds =================
template<int OUT_BF16, int HAS_BIAS, int NT, int SWZ>
__global__ __launch_bounds__(256)
void gemm_mfma(const ushort_t* __restrict__ A, int lda,
               const ushort_t* __restrict__ BT, int ldb,
               void* __restrict__ Cout, int ldc,
               int N, int K, const float* __restrict__ bias)
{
    __shared__ ushort_t As[2][4096];
    __shared__ ushort_t Bs[2][4096];
    int bm, bn;
    if (SWZ){
        int bid = blockIdx.x;
        int swz = (bid & 7)*190 + (bid >> 3);
        int mt = swz % 19, nt = swz / 19;
        if (nt >= 79) return;
        bm = mt*128; bn = nt*128;
    } else {
        bm = blockIdx.y * 128; bn = blockIdx.x * 128;
    }
    const int tid = threadIdx.x;
    const int lane = tid & 63;
    const int wave = tid >> 6;
    const int wm = (wave >> 1) * 64;
    const int wn = (wave & 1) * 64;
    const int lrow = lane & 15;
    const int lk8  = (lane >> 4) * 8;
    const int srow = tid >> 2;
    const int skq0 = (tid & 3) * 8;
    const int wbase = wave * 512;

    f32x4 acc[4][4];
    #pragma unroll
    for (int i=0;i<4;i++)
        #pragma unroll
        for (int j=0;j<4;j++) acc[i][j] = (f32x4){0.f,0.f,0.f,0.f};

    const ushort_t* Ab = A  + (size_t)(bm+srow)*lda + skq0;
    const ushort_t* Bb = BT + (size_t)(bn+srow)*ldb + skq0;

    GL16(Ab,                    &As[0][wbase]);
    GL16(Ab + (size_t)64*lda,   &As[0][2048 + wbase]);
    GL16(Bb,                    &Bs[0][wbase]);
    GL16(Bb + (size_t)64*ldb,   &Bs[0][2048 + wbase]);

    int buf = 0;
    for (int k0 = 0; k0 < K; k0 += 32) {
        asm volatile("s_waitcnt vmcnt(0)" ::: "memory");
        __syncthreads();
        if (k0 + 32 < K){
            int nb = buf ^ 1;
            GL16(Ab + k0 + 32,                  &As[nb][wbase]);
            GL16(Ab + (size_t)64*lda + k0 + 32, &As[nb][2048 + wbase]);
            GL16(Bb + k0 + 32,                  &Bs[nb][wbase]);
            GL16(Bb + (size_t)64*ldb + k0 + 32, &Bs[nb][2048 + wbase]);
        }
        bf16x8 af[4], bfr[4];
        #pragma unroll
        for (int i=0;i<4;i++) af[i]  = *(bf16x8*)&As[buf][(wm + i*16 + lrow)*32 + lk8];
        #pragma unroll
        for (int j=0;j<4;j++) bfr[j] = *(bf16x8*)&Bs[buf][(wn + j*16 + lrow)*32 + lk8];
        #pragma unroll
        for (int i=0;i<4;i++)
            #pragma unroll
            for (int j=0;j<4;j++)
                acc[i][j] = __builtin_amdgcn_mfma_f32_16x16x32_bf16(af[i], bfr[j], acc[i][j], 0, 0, 0);
        buf ^= 1;
    }

    const int rq = (lane >> 4) * 4;
    #pragma unroll
    for (int j=0;j<4;j++){
        int col = bn + wn + j*16 + lrow;
        if (col >= N) continue;
        float bv = HAS_BIAS ? bias[col] : 0.f;
        #pragma unroll
        for (int i=0;i<4;i++){
            #pragma unroll
            for (int q=0;q<4;q++){
                int row = bm + wm + i*16 + rq + q;
                float v = acc[i][j][q] + bv;
                if (OUT_BF16) ((ushort_t*)Cout)[(size_t)row*ldc + col] = f2b(v);
                else if (NT)  __builtin_nontemporal_store(v, &((float*)Cout)[(size_t)row*ldc + col]);
                else          ((float*)Cout)[(size_t)row*ldc + col] = v;
            }
        }
    }
}

// ================= dual GEMM (wa + embWih in one dispatch), runtime job =================
struct GJob { const ushort_t* A; int lda; const ushort_t* BT; int ldb;
              void* C; int ldc; int N, K; const float* bias; int out_bf16; int nx; int nblk; };

__global__ __launch_bounds__(256) void gemm_dual_k(GJob j0, GJob j1){
    __shared__ ushort_t As[2][4096];
    __shared__ ushort_t Bs[2][4096];
    int bid = blockIdx.x;
    GJob jb = (bid < j0.nblk) ? j0 : j1;
    if (bid >= j0.nblk) bid -= j0.nblk;
    const int bn = (bid % jb.nx)*128, bm = (bid / jb.nx)*128;
    const int tid = threadIdx.x;
    const int lane = tid & 63;
    const int wave = tid >> 6;
    const int wm = (wave >> 1) * 64;
    const int wn = (wave & 1) * 64;
    const int lrow = lane & 15;
    const int lk8  = (lane >> 4) * 8;
    const int srow = tid >> 2;
    const int skq0 = (tid & 3) * 8;
    const int wbase = wave * 512;

    f32x4 acc[4][4];
    #pragma unroll
    for (int i=0;i<4;i++)
        #pragma unroll
        for (int j=0;j<4;j++) acc[i][j] = (f32x4){0.f,0.f,0.f,0.f};

    const ushort_t* Ab = jb.A  + (size_t)(bm+srow)*jb.lda + skq0;
    const ushort_t* Bb = jb.BT + (size_t)(bn+srow)*jb.ldb + skq0;

    GL16(Ab,                        &As[0][wbase]);
    GL16(Ab + (size_t)64*jb.lda,    &As[0][2048 + wbase]);
    GL16(Bb,                        &Bs[0][wbase]);
    GL16(Bb + (size_t)64*jb.ldb,    &Bs[0][2048 + wbase]);

    int buf = 0;
    for (int k0 = 0; k0 < jb.K; k0 += 32) {
        asm volatile("s_waitcnt vmcnt(0)" ::: "memory");
        __syncthreads();
        if (k0 + 32 < jb.K){
            int nb = buf ^ 1;
            GL16(Ab + k0 + 32,                      &As[nb][wbase]);
            GL16(Ab + (size_t)64*jb.lda + k0 + 32,  &As[nb][2048 + wbase]);
            GL16(Bb + k0 + 32,                      &Bs[nb][wbase]);
            GL16(Bb + (size_t)64*jb.ldb + k0 + 32,  &Bs[nb][2048 + wbase]);
        }
        bf16x8 af[4], bfr[4];
        #pragma unroll
        for (int i=0;i<4;i++) af[i]  = *(bf16x8*)&As[buf][(wm + i*16 + lrow)*32 + lk8];
        #pragma unroll
        for (int j=0;j<4;j++) bfr[j] = *(bf16x8*)&Bs[buf][(wn + j*16 + lrow)*32 + lk8];
        #pragma unroll
        for (int i=0;i<4;i++)
            #pragma unroll
            for (int j=0;j<4;j++)
                acc[i][j] = __builtin_amdgcn_mfma_f32_16x16x32_bf16(af[i], bfr[j], acc[i][j], 0, 0, 0);
        buf ^= 1;
    }

    const int rq = (lane >> 4) * 4;
    #pragma unroll
    for (int j=0;j<4;j++){
        int col = bn + wn + j*16 + lrow;
        if (col >= jb.N) continue;
        float bv = jb.bias ? jb.bias[col] : 0.f;
        #pragma unroll
        for (int i=0;i<4;i++){
            #pragma unroll
            for (int q=0;q<4;q++){
                int row = bm + wm + i*16 + rq + q;
                float v = acc[i][j][q] + bv;
                if (jb.out_bf16) ((ushort_t*)jb.C)[(size_t)row*jb.ldc + col] = f2b(v);
                else             ((float*)jb.C)[(size_t)row*jb.ldc + col] = v;
            }
        }
    }
}

// ===== f32 tile GEMM (init path): C = tanh((Σ mcp partials)/L @ B + bias), z picks job =====
__global__ __launch_bounds__(256) void gemm64t2(const float* __restrict__ Amcp, int lda,
                       const float* __restrict__ B0, const float* __restrict__ B1, int ldb,
                       float* __restrict__ C0, float* __restrict__ C1, int ldc,
                       const float* __restrict__ bias0, const float* __restrict__ bias1)
{
    const float* Bm  = blockIdx.z ? B1 : B0;
    float* C         = blockIdx.z ? C1 : C0;
    const float* bias= blockIdx.z ? bias1 : bias0;
    __shared__ float As[16][65];
    __shared__ float Bs[16][65];
    int bm = blockIdx.y*64, bn = blockIdx.x*64;
    int tid = threadIdx.x;
    int tx = tid & 15, ty = tid >> 4;
    const float invL = 1.f/(float)L_;
    float acc[4][4] = {};
    for (int k0 = 0; k0 < D_; k0 += 16) {
        {
            int r  = tid >> 2;
            int kq = (tid & 3) * 4;
            const float* Ap = Amcp + (size_t)(bm+r)*lda + k0 + kq;
            float4 v0 = *(const float4*)(Ap);
            float4 v1 = *(const float4*)(Ap + 65536);
            float4 v2 = *(const float4*)(Ap + 131072);
            float4 v3 = *(const float4*)(Ap + 196608);
            float4 va = make_float4((v0.x+v1.x+v2.x+v3.x)*invL, (v0.y+v1.y+v2.y+v3.y)*invL,
                                    (v0.z+v1.z+v2.z+v3.z)*invL, (v0.w+v1.w+v2.w+v3.w)*invL);
            As[kq+0][r]=va.x; As[kq+1][r]=va.y; As[kq+2][r]=va.z; As[kq+3][r]=va.w;
        }
        {
            int kk = tid >> 4;
            int nq = (tid & 15) * 4;
            float4 vb = *(const float4*)(Bm + (size_t)(k0+kk)*ldb + bn + nq);
            Bs[kk][nq+0]=vb.x; Bs[kk][nq+1]=vb.y; Bs[kk][nq+2]=vb.z; Bs[kk][nq+3]=vb.w;
        }
        __syncthreads();
        #pragma unroll
        for (int k = 0; k < 16; ++k) {
            float a0[4], b0[4];
            #pragma unroll
            for (int i=0;i<4;i++) a0[i] = As[k][ty*4+i];
            #pragma unroll
            for (int j=0;j<4;j++) b0[j] = Bs[k][tx*4+j];
            #pragma unroll
            for (int i=0;i<4;i++)
                #pragma unroll
                for (int j=0;j<4;j++)
                    acc[i][j] = fmaf(a0[i], b0[j], acc[i][j]);
        }
        __syncthreads();
    }
    #pragma unroll
    for (int i=0;i<4;i++){
        int row = bm + ty*4 + i;
        #pragma unroll
        for (int j=0;j<4;j++){
            int col = bn + tx*4 + j;
            C[(size_t)row*ldc + col] = fast_tanh(acc[i][j] + bias[col]);
        }
    }
}

// ================= fused prep: mean/cvt FIRST + 6 transposes + bias/bars + emb gather =================
struct TJob { const float* src; const float* src2; ushort_t* dst;
              int lds, Ksz, Nsz, koff, ldk, nx, nblk; };
struct PrepArgs {
    TJob j[6];
    const float* a; ushort_t* a_b; float* mcp;
    const float* b_ih; const float* b_hh; float* bias4h; unsigned* bars;
    const int* caps; const float* embW; ushort_t* xemb;
};

__global__ __launch_bounds__(256) void prep_all_k(PrepArgs P){
    __shared__ float t[32][33];
    int bid = blockIdx.x;
    const int tid = threadIdx.x;
    if (bid < 256){
        const int b = bid >> 1, half = bid & 1;
        const int quad = tid & 127;
        const int sl = tid >> 7;
        const int pi = half*2 + sl;
        const int l0 = half*LH + sl*49;
        const float* p = P.a + ((size_t)(b*L_ + l0))*D_ + quad*4;
        ushort_t* q = P.a_b + ((size_t)(b*L_ + l0))*D_ + quad*4;
        float4 s = make_float4(0.f,0.f,0.f,0.f);
        for (int l=0;l<49;l++){
            float4 v = *(const float4*)(p + (size_t)l*D_);
            s.x += v.x; s.y += v.y; s.z += v.z; s.w += v.w;
            ushort_t r[4] = {f2b(v.x),f2b(v.y),f2b(v.z),f2b(v.w)};
            *(uint2*)(q + (size_t)l*D_) = *(uint2*)r;
        }
        *(float4*)(P.mcp + (size_t)pi*65536 + (size_t)b*D_ + quad*4) = s;
        return;
    }
    bid -= 256;
    if (bid < 8128){
        int ji = 0;
        while (bid >= P.j[ji].nblk){ bid -= P.j[ji].nblk; ji++; }
        const TJob jb = P.j[ji];
        int n0 = (bid % jb.nx)*32, k0 = (bid / jb.nx)*32;
        int tx = tid & 31, ty = tid >> 5;
        #pragma unroll
        for (int kk = ty; kk < 32; kk += 8){
            int k = k0 + kk, n = n0 + tx;
            float v = 0.f;
            if (k < jb.Ksz && n < jb.Nsz){
                v = jb.src[(size_t)k*jb.lds + n];
                if (jb.src2) v += jb.src2[(size_t)k*jb.lds + n];
            }
            t[kk][tx] = v;
        }
        __syncthreads();
        #pragma unroll
        for (int nn = ty; nn < 32; nn += 8){
            int n = n0 + nn, k = k0 + tx;
            if (k < jb.Ksz) jb.dst[(size_t)n*jb.ldk + jb.koff + k] = f2b(t[tx][nn]);
        }
        return;
    }
    bid -= 8128;
    if (bid == 0){
        for (int k = tid; k < G4H; k += 256) P.bias4h[k] = P.b_ih[k] + P.b_hh[k];
        P.bars[tid] = 0u;   // ebar[0..127], gbar at [128], rest scratch
        return;
    }
    bid -= 1;
    int i = bid*4 + (tid >> 6);
    int lane = tid & 63;
    int tt = i / B_, b = i - tt*B_;
    int cap = P.caps[b*T_ + tt];
    float4 v = ((const float4*)(P.embW + (size_t)cap*E_))[lane];
    ushort_t r[4] = {f2b(v.x),f2b(v.y),f2b(v.z),f2b(v.w)};
    *(uint2*)(P.xemb + (size_t)i*E_ + lane*4) = *(uint2*)r;
}

// h0: cvt to xcat + full hWp0 + zero hWp1 + beta-dot; grid B x 512
__global__ __launch_bounds__(512) void hw0cvt_k(const float* __restrict__ h0f,
                        const ushort_t* __restrict__ WhcT, const float* __restrict__ beta_W,
                        ushort_t* __restrict__ xcat, float* __restrict__ hWp, float* __restrict__ bdot){
    int b = blockIdx.x, tid = threadIdx.x;
    int lane = tid & 63, wave = tid >> 6;
    __shared__ ushort_t hls[512];
    __shared__ float rr[8];
    float hv = h0f[b*H_ + tid];
    ushort_t hb = f2b(hv);
    xcat[(size_t)b*KCAT + D_ + tid] = hb;
    hls[tid] = hb;
    hWp[(size_t)(b*2+1)*512 + tid] = 0.f;
    float dv = hv * beta_W[tid];
    #pragma unroll
    for (int off=32; off; off>>=1) dv += __shfl_down(dv, off);
    if (lane==0) rr[wave] = dv;
    __syncthreads();
    if (tid == 0){
        float s = rr[0]+rr[1]+rr[2]+rr[3]+rr[4]+rr[5]+rr[6]+rr[7];
        bdot[b*2] = s; bdot[b*2+1] = 0.f;
    }
    int wn = wave * 64;
    int col16 = lane & 15;
    int khi = (lane >> 4) * 8;
    bool a_on = (col16 == 0);
    f32x4 acc[4];
    #pragma unroll
    for (int f=0;f<4;f++) acc[f] = (f32x4){0.f,0.f,0.f,0.f};
    for (int kk=0; kk<16; kk++){
        bf16x8 af = (bf16x8){0,0,0,0,0,0,0,0};
        if (a_on) af = *(const bf16x8*)&hls[kk*32 + khi];
        #pragma unroll
        for (int f=0;f<4;f++){
            bf16x8 bf = *(const bf16x8*)(WhcT + (size_t)(wn + f*16 + col16)*512 + kk*32 + khi);
            acc[f] = __builtin_amdgcn_mfma_f32_16x16x32_bf16(af, bf, acc[f], 0, 0, 0);
        }
    }
    if (lane < 16){
        #pragma unroll
        for (int f=0;f<4;f++) hWp[(size_t)(b*2+0)*512 + wn + f*16 + lane] = acc[f][0];
    }
}

// ========== merged step: lstm(t-1) + hW + attn(t) + ctx -> grid sync -> gates(t) ==========
// grid 256 x 512; blk = b*2+half for phases L/E/SM; blk = (ks<<5)|bn-tile for gates
__global__ __launch_bounds__(512) void mega_k(const ushort_t* __restrict__ wa,
                        const ushort_t* __restrict__ a_b,
                        const float* __restrict__ v,
                        const float* __restrict__ beta_W, const float* __restrict__ beta_b,
                        const ushort_t* __restrict__ WhcT, const ushort_t* __restrict__ WcatT,
                        const float* __restrict__ embWih,
                        float* __restrict__ cbuf, float* __restrict__ hWp,
                        ushort_t* __restrict__ xcat, ushort_t* __restrict__ Hall,
                        float* __restrict__ alphas_out, float* __restrict__ ebuf,
                        float* __restrict__ gp,
                        unsigned* __restrict__ ebar, unsigned* __restrict__ gbar,
                        float* __restrict__ bdot, int t)
{
    const int blk = blockIdx.x;
    const int b = blk >> 1, half = blk & 1;
    const int tid = threadIdx.x;
    const int lane = tid & 63, wave = tid >> 6;
    __shared__ ushort_t hls[256];
    __shared__ float red[16];
    __shared__ float al_s[224];
    __shared__ float4 part4[8][64];
    __shared__ ushort_t As[128*32];
    __shared__ ushort_t Bs[64*32];

    // ---- phase L: lstm(t-1) for own j-half + beta partial + hW K-partial (skip at t==0) ----
    if (t > 0){
        float dv = 0.f;
        if (tid < 256){
            const int j = half*256 + tid;
            const float* eb = embWih + ((size_t)((t-1)*B_ + b))*G4H;
            float gi = eb[j], gf = eb[H_+j], gg = eb[2*H_+j], go = eb[3*H_+j];
            #pragma unroll
            for (int ks=0; ks<8; ks++){
                const float* g = gp + ((size_t)(ks*B_ + b))*G4H;
                gi += g[j]; gf += g[H_+j]; gg += g[2*H_+j]; go += g[3*H_+j];
            }
            float ig = sigmoidf_(gi), fg = sigmoidf_(gf);
            float g2 = fast_tanh(gg), og = sigmoidf_(go);
            float c = fg*cbuf[b*H_+j] + ig*g2;
            float h = og*fast_tanh(c);
            cbuf[b*H_+j] = c;
            ushort_t hb = f2b(h);
            xcat[(size_t)b*KCAT + D_ + j] = hb;
            Hall[((size_t)(t-1)*B_ + b)*H_ + j] = hb;
            hls[tid] = hb;
            dv = h * beta_W[j];
        }
        #pragma unroll
        for (int off=32; off; off>>=1) dv += __shfl_down(dv, off);
        if (lane==0) red[wave] = dv;
        __syncthreads();
        // hWp[half] = h_half @ Whc[half*256 : half*256+256, :]
        int wn = wave * 64;
        int col16 = lane & 15;
        int khi = (lane >> 4) * 8;
        bool a_on = (col16 == 0);
        f32x4 acc[4];
        #pragma unroll
        for (int f=0;f<4;f++) acc[f] = (f32x4){0.f,0.f,0.f,0.f};
        #pragma unroll
        for (int kk=0; kk<8; kk++){
            bf16x8 af = (bf16x8){0,0,0,0,0,0,0,0};
            if (a_on) af = *(const bf16x8*)&hls[kk*32 + khi];
            #pragma unroll
            for (int f=0;f<4;f++){
                bf16x8 bf = *(const bf16x8*)(WhcT + (size_t)(wn + f*16 + col16)*512 + half*256 + kk*32 + khi);
                acc[f] = __builtin_amdgcn_mfma_f32_16x16x32_bf16(af, bf, acc[f], 0, 0, 0);
            }
        }
        if (lane < 16){
            #pragma unroll
            for (int f=0;f<4;f++) hWp[(size_t)(b*2+half)*512 + wn + f*16 + lane] = acc[f][0];
        }
    }
    // ---- pair sync 1 ----
    __syncthreads();
    if (tid == 0){
        if (t > 0) bdot[b*2+half] = red[0]+red[1]+red[2]+red[3];
        __threadfence();
        atomicAdd(&ebar[b], 1u);
        const unsigned tgt = 2u*(unsigned)(2*t+1);
        while (__hip_atomic_load(&ebar[b], __ATOMIC_ACQUIRE, __HIP_MEMORY_SCOPE_AGENT) < tgt)
            __builtin_amdgcn_s_sleep(1);
    }
    __syncthreads();
    // ---- phase E: e over own l-half ----
    {
        const float* hp0 = hWp + (size_t)(b*2+0)*512 + lane*8;
        const float* hp1 = hWp + (size_t)(b*2+1)*512 + lane*8;
        float4 p00 = *(const float4*)hp0, p01 = *(const float4*)(hp0+4);
        float4 p10 = *(const float4*)hp1, p11 = *(const float4*)(hp1+4);
        float4 hw0 = make_float4(p00.x+p10.x, p00.y+p10.y, p00.z+p10.z, p00.w+p10.w);
        float4 hw1 = make_float4(p01.x+p11.x, p01.y+p11.y, p01.z+p11.z, p01.w+p11.w);
        const float* vp = v + lane*8;
        float4 v0 = *(const float4*)vp, v1 = *(const float4*)(vp+4);
        const int l0 = half*LH;
        for (int r = wave; r < LH; r += 8){
            int4 raw = *(const int4*)(wa + (((size_t)(b*L_ + l0 + r))<<9) + lane*8);
            const unsigned* u = (const unsigned*)&raw;
            float s;
            s  = fast_tanh(b2f_lo(u[0]) + hw0.x)*v0.x;
            s += fast_tanh(b2f_hi(u[0]) + hw0.y)*v0.y;
            s += fast_tanh(b2f_lo(u[1]) + hw0.z)*v0.z;
            s += fast_tanh(b2f_hi(u[1]) + hw0.w)*v0.w;
            s += fast_tanh(b2f_lo(u[2]) + hw1.x)*v1.x;
            s += fast_tanh(b2f_hi(u[2]) + hw1.y)*v1.y;
            s += fast_tanh(b2f_lo(u[3]) + hw1.z)*v1.z;
            s += fast_tanh(b2f_hi(u[3]) + hw1.w)*v1.w;
            #pragma unroll
            for (int off=32; off; off>>=1) s += __shfl_down(s, off);
            if (lane==0) ebuf[b*L_ + l0 + r] = s;
        }
    }
    // ---- pair sync 2 ----
    __syncthreads();
    if (tid == 0){
        __threadfence();
        atomicAdd(&ebar[b], 1u);
        const unsigned tgt = 2u*(unsigned)(2*t+2);
        while (__hip_atomic_load(&ebar[b], __ATOMIC_ACQUIRE, __HIP_MEMORY_SCOPE_AGENT) < tgt)
            __builtin_amdgcn_s_sleep(1);
    }
    __syncthreads();
    // ---- softmax over all 196: wave-level reduces ----
    float ev = (tid < L_) ? ebuf[b*L_ + tid] : -3.0e38f;
    float wmax = ev;
    #pragma unroll
    for (int off=32; off; off>>=1) wmax = fmaxf(wmax, __shfl_down(wmax, off));
    if (lane==0) red[wave] = wmax;
    __syncthreads();
    float m = fmaxf(fmaxf(fmaxf(red[0],red[1]),fmaxf(red[2],red[3])),
                    fmaxf(fmaxf(red[4],red[5]),fmaxf(red[6],red[7])));
    float pr = (tid < L_) ? __expf(ev - m) : 0.f;
    float wsum = pr;
    #pragma unroll
    for (int off=32; off; off>>=1) wsum += __shfl_down(wsum, off);
    if (lane==0) red[8+wave] = wsum;
    __syncthreads();
    float inv = 1.f / (red[8]+red[9]+red[10]+red[11]+red[12]+red[13]+red[14]+red[15]);
    if (tid < L_) al_s[tid] = pr*inv;
    const int l0 = half*LH;
    if (tid >= l0 && tid < l0 + LH)
        __builtin_nontemporal_store(pr*inv, alphas_out + (size_t)b*TM1*L_ + (size_t)t*L_ + tid);
    __syncthreads();
    // ---- ctx: 256 d's per block, 4 d's per thread (uint2), 8-way l split ----
    {
        const int dg = tid & 63;
        const int lr = tid >> 6;
        const int d0 = half*256 + dg*4;
        const ushort_t* pa = a_b + (((size_t)(b*L_))<<9) + d0;
        float4 s = make_float4(0.f,0.f,0.f,0.f);
        for (int l = lr; l < L_; l += 8){
            uint2 av = *(const uint2*)(pa + ((size_t)l<<9));
            float al = al_s[l];
            s.x = fmaf(al, b2f_lo(av.x), s.x);
            s.y = fmaf(al, b2f_hi(av.x), s.y);
            s.z = fmaf(al, b2f_lo(av.y), s.z);
            s.w = fmaf(al, b2f_hi(av.y), s.w);
        }
        part4[lr][dg] = s;
        __syncthreads();
        if (tid < 64){
            float beta = sigmoidf_(bdot[b*2] + bdot[b*2+1] + beta_b[0]);
            float4 r = make_float4(0.f,0.f,0.f,0.f);
            #pragma unroll
            for (int q=0;q<8;q++){
                float4 pv = part4[q][tid];
                r.x += pv.x; r.y += pv.y; r.z += pv.z; r.w += pv.w;
            }
            unsigned lo = (unsigned)f2b(beta*r.x) | (((unsigned)f2b(beta*r.y))<<16);
            unsigned hi = (unsigned)f2b(beta*r.z) | (((unsigned)f2b(beta*r.w))<<16);
            uint2 pk; pk.x = lo; pk.y = hi;
            *(uint2*)(xcat + (size_t)b*KCAT + half*256 + tid*4) = pk;
        }
    }
    // ---- grid sync: all ctx/h visible ----
    __syncthreads();
    if (tid == 0){
        __threadfence();
        atomicAdd(gbar, 1u);
        const unsigned tgt = 256u*(unsigned)(t+1);
        while (__hip_atomic_load(gbar, __ATOMIC_ACQUIRE, __HIP_MEMORY_SCOPE_AGENT) < tgt)
            __builtin_amdgcn_s_sleep(1);
    }
    __syncthreads();
    // ---- phase G: gates partials; block = (bn = blk&31, ks = blk>>5); tile 128x64, K=128 ----
    {
        const int bn = (blk & 31) * 64;
        const int ks = blk >> 5;
        const int wm = (wave & 3) * 32;
        const int wn = (wave >> 2) * 32;
        const int lrow = lane & 15, lk8 = (lane >> 4) * 8;
        const int ra = tid >> 2, kqa = (tid & 3)*8;
        f32x4 acc[2][2];
        #pragma unroll
        for (int i=0;i<2;i++)
            #pragma unroll
            for (int j=0;j<2;j++) acc[i][j] = (f32x4){0.f,0.f,0.f,0.f};
        #pragma unroll
        for (int kk = 0; kk < 4; ++kk){
            int k0 = ks*128 + kk*32;
            int4 av = *(const int4*)(xcat + (size_t)ra*KCAT + k0 + kqa);
            int4 bv;
            if (tid < 256) bv = *(const int4*)(WcatT + (size_t)(bn + ra)*KCAT + k0 + kqa);
            __syncthreads();
            *(int4*)&As[ra*32 + kqa] = av;
            if (tid < 256) *(int4*)&Bs[ra*32 + kqa] = bv;
            __syncthreads();
            bf16x8 af[2], bfr[2];
            #pragma unroll
            for (int i=0;i<2;i++) af[i]  = *(bf16x8*)&As[(wm + i*16 + lrow)*32 + lk8];
            #pragma unroll
            for (int j=0;j<2;j++) bfr[j] = *(bf16x8*)&Bs[(wn + j*16 + lrow)*32 + lk8];
            #pragma unroll
            for (int i=0;i<2;i++)
                #pragma unroll
                for (int j=0;j<2;j++)
                    acc[i][j] = __builtin_amdgcn_mfma_f32_16x16x32_bf16(af[i], bfr[j], acc[i][j], 0, 0, 0);
        }
        const int rq = (lane >> 4) * 4;
        #pragma unroll
        for (int i=0;i<2;i++)
            #pragma unroll
            for (int j=0;j<2;j++){
                int gcol = bn + wn + j*16 + lrow;
                #pragma unroll
                for (int q=0;q<4;q++){
                    int grow = wm + i*16 + rq + q;
                    gp[((size_t)(ks*B_ + grow))*G4H + gcol] = acc[i][j][q];
                }
            }
    }
}

// final lstm (h_19 -> Hall[18]); grid B x 512
__global__ __launch_bounds__(512) void lstmfin_k(const float* __restrict__ gp, const float* __restrict__ embWih,
                       const float* __restrict__ cbuf, ushort_t* __restrict__ Hall){
    int b = blockIdx.x, j = threadIdx.x;
    const float* eb = embWih + ((size_t)(18*B_ + b))*G4H;
    float gi = eb[j], gf = eb[H_+j], gg = eb[2*H_+j], go = eb[3*H_+j];
    #pragma unroll
    for (int ks=0; ks<8; ks++){
        const float* g = gp + ((size_t)(ks*B_ + b))*G4H;
        gi += g[j]; gf += g[H_+j]; gg += g[2*H_+j]; go += g[3*H_+j];
    }
    float ig = sigmoidf_(gi), fg = sigmoidf_(gf);
    float g2 = fast_tanh(gg), og = sigmoidf_(go);
    float c = fg*cbuf[b*H_+j] + ig*g2;
    float h = og*fast_tanh(c);
    Hall[((size_t)18*B_ + b)*H_ + j] = f2b(h);
}

extern "C" void kernel_launch(void* const* d_in, const int* in_sizes, int n_in,
                              void* d_out, int out_size, void* d_ws, size_t ws_size,
                              hipStream_t stream) {
    const float* a      = (const float*)d_in[0];
    const int*   caps   = (const int*)  d_in[1];
    const float* embW   = (const float*)d_in[3];
    const float* Wa     = (const float*)d_in[4];
    const float* Wh     = (const float*)d_in[5];
    const float* Wc     = (const float*)d_in[6];
    const float* v      = (const float*)d_in[7];
    const float* beta_W = (const float*)d_in[8];
    const float* beta_b = (const float*)d_in[9];
    const float* W_ih   = (const float*)d_in[10];
    const float* W_hh   = (const float*)d_in[11];
    const float* b_ih   = (const float*)d_in[12];
    const float* b_hh   = (const float*)d_in[13];
    const float* fc_W   = (const float*)d_in[14];
    const float* fc_b   = (const float*)d_in[15];
    const float* iWh    = (const float*)d_in[16];
    const float* ibh    = (const float*)d_in[17];
    const float* iWc    = (const float*)d_in[18];
    const float* ibc    = (const float*)d_in[19];

    float* out    = (float*)d_out;
    float* alphas = out + (size_t)ROWS*V_;

    // d_out scratch (dead before final logits GEMM overwrites it)
    char* ob = (char*)d_out;
    ushort_t* wa_b   = (ushort_t*)(ob);               // 25,690,112 B
    ushort_t* a_b    = (ushort_t*)(ob + 25690112);    // 25,690,112 B
    float*    embWih = (float*)   (ob + 51380224);    // 19,922,944 B

    // d_ws layout (byte offsets)
    char* wb = (char*)d_ws;
    float* mcp      = (float*)(wb);              // 1,048,576
    float* bdot     = (float*)(wb + 1048576);    // 4096
    float* cbuf     = (float*)(wb + 1052672);    // 262144
    float* h0f      = (float*)(wb + 1314816);    // 262144
    float* hWp      = (float*)(wb + 1576960);    // 524288
    float* ebuf     = (float*)(wb + 2101248);    // 102400
    float* bias4h   = (float*)(wb + 2203648);    // 8192
    unsigned* bars  = (unsigned*)(wb + 2211840); // 4096: ebar[0..127], gbar = bars+128
    float* gp       = (float*)(wb + 2215936);    // 8388608
    ushort_t* xcat_b = (ushort_t*)(wb + 10604544);  // 262144
    ushort_t* xemb_b = (ushort_t*)(wb + 10866688);  // 1245184
    ushort_t* Hall   = (ushort_t*)(wb + 12111872);  // 2490368
    ushort_t* WaT    = (ushort_t*)(wb + 14602240);  // 524288
    ushort_t* WhcT   = (ushort_t*)(wb + 15126528);  // 524288
    ushort_t* WihT   = (ushort_t*)(wb + 15650816);  // 1048576
    ushort_t* WcatT  = (ushort_t*)(wb + 16699392);  // 4194304
    ushort_t* fcWT   = (ushort_t*)(wb + 20893696);  // 10354688 -> ends ~29.8MB

    // ---- prep (1 launch; mean blocks first so they overlap the transposes) ----
    PrepArgs P;
    P.j[0] = { Wa,   nullptr, WaT,  512, 512, 512,  0,   512,  16, 256 };
    P.j[1] = { Wh,   Wc,      WhcT, 512, 512, 512,  0,   512,  16, 256 };
    P.j[2] = { W_ih, nullptr, WihT, G4H, 256, G4H,  0,   256,  64, 512 };
    P.j[3] = { W_ih + (size_t)E_*G4H, nullptr, WcatT, G4H, 512, G4H, 0,   KCAT, 64, 1024 };
    P.j[4] = { W_hh, nullptr, WcatT, G4H, 512, G4H,  512, KCAT, 64, 1024 };
    P.j[5] = { fc_W, nullptr, fcWT, V_,  512, V_,   0,   512,  316, 5056 };
    P.a = a; P.a_b = a_b; P.mcp = mcp;
    P.b_ih = b_ih; P.b_hh = b_hh; P.bias4h = bias4h; P.bars = bars;
    P.caps = caps; P.embW = embW; P.xemb = xemb_b;
    prep_all_k<<<8993, 256, 0, stream>>>(P);

    gemm64t2<<<dim3(8,2,2), 256, 0, stream>>>(mcp, D_, iWh, iWc, H_, h0f, cbuf, H_, ibh, ibc);
    hw0cvt_k<<<B_, 512, 0, stream>>>(h0f, WhcT, beta_W, xcat_b, hWp, bdot);

    // wa_b + embWih in one dispatch
    GJob g0 = { a_b,    512, WaT,  512, wa_b,   512, 512,  512, nullptr, 1, 4,  784 };
    GJob g1 = { xemb_b, 256, WihT, 256, embWih, G4H, G4H,  256, bias4h,  0, 16, 304 };
    gemm_dual_k<<<1088, 256, 0, stream>>>(g0, g1);

    // ---- loop: 1 kernel/step (merged attn+gates with internal grid sync) ----
    for (int t = 0; t < TM1; ++t){
        mega_k<<<256, 512, 0, stream>>>(wa_b, a_b, v, beta_W, beta_b, WhcT, WcatT,
                                        embWih, cbuf, hWp, xcat_b, Hall,
                                        alphas, ebuf, gp, bars, bars + 128, bdot, t);
    }
    lstmfin_k<<<B_, 512, 0, stream>>>(gp, embWih, cbuf, Hall);

    // logits = Hall @ fc_W + fc_b   (2432 x 10000 x 512), NT stores + XCD swizzle
    gemm_mfma<0,1,1,1><<<dim3(1520), 256, 0, stream>>>(Hall, H_, fcWT, H_, out, V_, V_, H_, fc_b);
}

// Round 15
// 977.383 us; speedup vs baseline: 1.4728x; 1.4728x over previous
//
#include <hip/hip_runtime.h>
#include <hip/hip_bf16.h>
#include <math.h>

#define B_ 128
#define L_ 196
#define D_ 512
#define T_ 20
#define V_ 10000
#define E_ 256
#define H_ 512
#define A_ 512
#define TM1 19
#define ROWS (TM1*B_)      /* 2432 */
#define G4H 2048
#define KCAT 1024
#define LH 98

typedef unsigned short ushort_t;
typedef __attribute__((ext_vector_type(8))) short bf16x8;
typedef __attribute__((ext_vector_type(4))) float f32x4;

__device__ __forceinline__ float fast_tanh(float x){
    float ax = fabsf(x);
    float e = __expf(-2.f*ax);
    float r = __builtin_amdgcn_rcpf(1.f + e);
    return copysignf((1.f - e)*r, x);
}
__device__ __forceinline__ float sigmoidf_(float x){
    return __builtin_amdgcn_rcpf(1.f + __expf(-x));
}
__device__ __forceinline__ ushort_t f2b(float f){
    union{float f; unsigned u;} x; x.f = f;
    unsigned r = x.u + 0x7fffu + ((x.u>>16)&1u);
    return (ushort_t)(r>>16);
}
__device__ __forceinline__ float b2f(ushort_t h){
    union{unsigned u; float f;} x; x.u = ((unsigned)h)<<16;
    return x.f;
}
__device__ __forceinline__ float b2f_lo(unsigned u){ union{unsigned u; float f;} x; x.u = u<<16; return x.f; }
__device__ __forceinline__ float b2f_hi(unsigned u){ union{unsigned u; float f;} x; x.u = u & 0xffff0000u; return x.f; }

#define GL16(gsrc, ldst) __builtin_amdgcn_global_load_lds( \
    (const __attribute__((address_space(1))) unsigned*)(gsrc), \
    (__attribute__((address_space(3))) unsigned*)(ldst), 16, 0, 0)

// ========== logits GEMM: dbuf global_load_lds + XCD swizzle + LDS-coalesced NT epilogue ==========
__global__ __launch_bounds__(256)
void gemm_logits_k(const ushort_t* __restrict__ A, int lda,
                   const ushort_t* __restrict__ BT, int ldb,
                   float* __restrict__ C, int ldc,
                   int N, int K, const float* __restrict__ bias)
{
    __shared__ ushort_t As[2][4096];
    __shared__ ushort_t Bs[2][4096];
    int bid = blockIdx.x;
    int swz = (bid & 7)*190 + (bid >> 3);
    int mt = swz % 19, nt = swz / 19;
    if (nt >= 79) return;
    const int bm = mt*128, bn = nt*128;
    const int tid = threadIdx.x;
    const int lane = tid & 63;
    const int wave = tid >> 6;
    const int wm = (wave >> 1) * 64;
    const int wn = (wave & 1) * 64;
    const int lrow = lane & 15;
    const int lk8  = (lane >> 4) * 8;
    const int srow = tid >> 2;
    const int skq0 = (tid & 3) * 8;
    const int wbase = wave * 512;

    f32x4 acc[4][4];
    #pragma unroll
    for (int i=0;i<4;i++)
        #pragma unroll
        for (int j=0;j<4;j++) acc[i][j] = (f32x4){0.f,0.f,0.f,0.f};

    const ushort_t* Ab = A  + (size_t)(bm+srow)*lda + skq0;
    const ushort_t* Bb = BT + (size_t)(bn+srow)*ldb + skq0;

    GL16(Ab,                    &As[0][wbase]);
    GL16(Ab + (size_t)64*lda,   &As[0][2048 + wbase]);
    GL16(Bb,                    &Bs[0][wbase]);
    GL16(Bb + (size_t)64*ldb,   &Bs[0][2048 + wbase]);

    int buf = 0;
    for (int k0 = 0; k0 < K; k0 += 32) {
        asm volatile("s_waitcnt vmcnt(0)" ::: "memory");
        __syncthreads();
        if (k0 + 32 < K){
            int nb = buf ^ 1;
            GL16(Ab + k0 + 32,                  &As[nb][wbase]);
            GL16(Ab + (size_t)64*lda + k0 + 32, &As[nb][2048 + wbase]);
            GL16(Bb + k0 + 32,                  &Bs[nb][wbase]);
            GL16(Bb + (size_t)64*ldb + k0 + 32, &Bs[nb][2048 + wbase]);
        }
        bf16x8 af[4], bfr[4];
        #pragma unroll
        for (int i=0;i<4;i++) af[i]  = *(bf16x8*)&As[buf][(wm + i*16 + lrow)*32 + lk8];
        #pragma unroll
        for (int j=0;j<4;j++) bfr[j] = *(bf16x8*)&Bs[buf][(wn + j*16 + lrow)*32 + lk8];
        #pragma unroll
        for (int i=0;i<4;i++)
            #pragma unroll
            for (int j=0;j<4;j++)
                acc[i][j] = __builtin_amdgcn_mfma_f32_16x16x32_bf16(af[i], bfr[j], acc[i][j], 0, 0, 0);
        buf ^= 1;
    }

    // epilogue: stage 32x128 f32 chunks in LDS, coalesced NT float4 stores
    const int rq = (lane >> 4) * 4;
    float* eps = (float*)As;
    #pragma unroll
    for (int c = 0; c < 4; ++c){
        __syncthreads();
        if ((wave >> 1) == (c >> 1)){
            const int ib = 2*(c & 1);
            #pragma unroll
            for (int ii = 0; ii < 2; ++ii){
                #pragma unroll
                for (int j = 0; j < 4; ++j){
                    #pragma unroll
                    for (int q = 0; q < 4; ++q){
                        int lr_ = ii*16 + rq + q;
                        int lc  = wn + j*16 + lrow;
                        eps[lr_*128 + lc] = acc[ib+ii][j][q];
                    }
                }
            }
        }
        __syncthreads();
        for (int it = tid; it < 1024; it += 256){
            int r = it >> 5, c4 = it & 31;
            int col0 = bn + c4*4;
            if (col0 >= N) continue;
            f32x4 vv = *(f32x4*)&eps[r*128 + c4*4];
            float* dst = &C[(size_t)(bm + 32*c + r)*ldc + col0];
            if (col0 + 3 < N){
                float4 bb = *(const float4*)(bias + col0);
                vv[0] += bb.x; vv[1] += bb.y; vv[2] += bb.z; vv[3] += bb.w;
                __builtin_nontemporal_store(vv, (f32x4*)dst);
            } else {
                for (int e=0; e<4 && col0+e < N; ++e)
                    __builtin_nontemporal_store(vv[e] + bias[col0+e], dst + e);
            }
        }
    }
}

// ================= dual GEMM (wa + embWih in one dispatch), runtime job =================
struct GJob { const ushort_t* A; int lda; const ushort_t* BT; int ldb;
              void* C; int ldc; int N, K; const float* bias; int out_bf16; int nx; int nblk; };

__global__ __launch_bounds__(256) void gemm_dual_k(GJob j0, GJob j1){
    __shared__ ushort_t As[2][4096];
    __shared__ ushort_t Bs[2][4096];
    int bid = blockIdx.x;
    GJob jb = (bid < j0.nblk) ? j0 : j1;
    if (bid >= j0.nblk) bid -= j0.nblk;
    const int bn = (bid % jb.nx)*128, bm = (bid / jb.nx)*128;
    const int tid = threadIdx.x;
    const int lane = tid & 63;
    const int wave = tid >> 6;
    const int wm = (wave >> 1) * 64;
    const int wn = (wave & 1) * 64;
    const int lrow = lane & 15;
    const int lk8  = (lane >> 4) * 8;
    const int srow = tid >> 2;
    const int skq0 = (tid & 3) * 8;
    const int wbase = wave * 512;

    f32x4 acc[4][4];
    #pragma unroll
    for (int i=0;i<4;i++)
        #pragma unroll
        for (int j=0;j<4;j++) acc[i][j] = (f32x4){0.f,0.f,0.f,0.f};

    const ushort_t* Ab = jb.A  + (size_t)(bm+srow)*jb.lda + skq0;
    const ushort_t* Bb = jb.BT + (size_t)(bn+srow)*jb.ldb + skq0;

    GL16(Ab,                        &As[0][wbase]);
    GL16(Ab + (size_t)64*jb.lda,    &As[0][2048 + wbase]);
    GL16(Bb,                        &Bs[0][wbase]);
    GL16(Bb + (size_t)64*jb.ldb,    &Bs[0][2048 + wbase]);

    int buf = 0;
    for (int k0 = 0; k0 < jb.K; k0 += 32) {
        asm volatile("s_waitcnt vmcnt(0)" ::: "memory");
        __syncthreads();
        if (k0 + 32 < jb.K){
            int nb = buf ^ 1;
            GL16(Ab + k0 + 32,                      &As[nb][wbase]);
            GL16(Ab + (size_t)64*jb.lda + k0 + 32,  &As[nb][2048 + wbase]);
            GL16(Bb + k0 + 32,                      &Bs[nb][wbase]);
            GL16(Bb + (size_t)64*jb.ldb + k0 + 32,  &Bs[nb][2048 + wbase]);
        }
        bf16x8 af[4], bfr[4];
        #pragma unroll
        for (int i=0;i<4;i++) af[i]  = *(bf16x8*)&As[buf][(wm + i*16 + lrow)*32 + lk8];
        #pragma unroll
        for (int j=0;j<4;j++) bfr[j] = *(bf16x8*)&Bs[buf][(wn + j*16 + lrow)*32 + lk8];
        #pragma unroll
        for (int i=0;i<4;i++)
            #pragma unroll
            for (int j=0;j<4;j++)
                acc[i][j] = __builtin_amdgcn_mfma_f32_16x16x32_bf16(af[i], bfr[j], acc[i][j], 0, 0, 0);
        buf ^= 1;
    }

    const int rq = (lane >> 4) * 4;
    #pragma unroll
    for (int j=0;j<4;j++){
        int col = bn + wn + j*16 + lrow;
        if (col >= jb.N) continue;
        float bv = jb.bias ? jb.bias[col] : 0.f;
        #pragma unroll
        for (int i=0;i<4;i++){
            #pragma unroll
            for (int q=0;q<4;q++){
                int row = bm + wm + i*16 + rq + q;
                float v = acc[i][j][q] + bv;
                if (jb.out_bf16) ((ushort_t*)jb.C)[(size_t)row*jb.ldc + col] = f2b(v);
                else             ((float*)jb.C)[(size_t)row*jb.ldc + col] = v;
            }
        }
    }
}

// ===== f32 tile GEMM (init path): C = tanh((Σ mcp partials)/L @ B + bias), z picks job =====
__global__ __launch_bounds__(256) void gemm64t2(const float* __restrict__ Amcp, int lda,
                       const float* __restrict__ B0, const float* __restrict__ B1, int ldb,
                       float* __restrict__ C0, float* __restrict__ C1, int ldc,
                       const float* __restrict__ bias0, const float* __restrict__ bias1)
{
    const float* Bm  = blockIdx.z ? B1 : B0;
    float* C         = blockIdx.z ? C1 : C0;
    const float* bias= blockIdx.z ? bias1 : bias0;
    __shared__ float As[16][65];
    __shared__ float Bs[16][65];
    int bm = blockIdx.y*64, bn = blockIdx.x*64;
    int tid = threadIdx.x;
    int tx = tid & 15, ty = tid >> 4;
    const float invL = 1.f/(float)L_;
    float acc[4][4] = {};
    for (int k0 = 0; k0 < D_; k0 += 16) {
        {
            int r  = tid >> 2;
            int kq = (tid & 3) * 4;
            const float* Ap = Amcp + (size_t)(bm+r)*lda + k0 + kq;
            float4 v0 = *(const float4*)(Ap);
            float4 v1 = *(const float4*)(Ap + 65536);
            float4 v2 = *(const float4*)(Ap + 131072);
            float4 v3 = *(const float4*)(Ap + 196608);
            float4 va = make_float4((v0.x+v1.x+v2.x+v3.x)*invL, (v0.y+v1.y+v2.y+v3.y)*invL,
                                    (v0.z+v1.z+v2.z+v3.z)*invL, (v0.w+v1.w+v2.w+v3.w)*invL);
            As[kq+0][r]=va.x; As[kq+1][r]=va.y; As[kq+2][r]=va.z; As[kq+3][r]=va.w;
        }
        {
            int kk = tid >> 4;
            int nq = (tid & 15) * 4;
            float4 vb = *(const float4*)(Bm + (size_t)(k0+kk)*ldb + bn + nq);
            Bs[kk][nq+0]=vb.x; Bs[kk][nq+1]=vb.y; Bs[kk][nq+2]=vb.z; Bs[kk][nq+3]=vb.w;
        }
        __syncthreads();
        #pragma unroll
        for (int k = 0; k < 16; ++k) {
            float a0[4], b0[4];
            #pragma unroll
            for (int i=0;i<4;i++) a0[i] = As[k][ty*4+i];
            #pragma unroll
            for (int j=0;j<4;j++) b0[j] = Bs[k][tx*4+j];
            #pragma unroll
            for (int i=0;i<4;i++)
                #pragma unroll
                for (int j=0;j<4;j++)
                    acc[i][j] = fmaf(a0[i], b0[j], acc[i][j]);
        }
        __syncthreads();
    }
    #pragma unroll
    for (int i=0;i<4;i++){
        int row = bm + ty*4 + i;
        #pragma unroll
        for (int j=0;j<4;j++){
            int col = bn + tx*4 + j;
            C[(size_t)row*ldc + col] = fast_tanh(acc[i][j] + bias[col]);
        }
    }
}

// ================= fused prep: mean/cvt FIRST + 6 transposes + bias/bars + emb gather =================
struct TJob { const float* src; const float* src2; ushort_t* dst;
              int lds, Ksz, Nsz, koff, ldk, nx, nblk; };
struct PrepArgs {
    TJob j[6];
    const float* a; ushort_t* a_b; float* mcp;
    const float* b_ih; const float* b_hh; float* bias4h; unsigned* bars;
    const int* caps; const float* embW; ushort_t* xemb;
};

__global__ __launch_bounds__(256) void prep_all_k(PrepArgs P){
    __shared__ float t[32][33];
    int bid = blockIdx.x;
    const int tid = threadIdx.x;
    if (bid < 256){
        const int b = bid >> 1, half = bid & 1;
        const int quad = tid & 127;
        const int sl = tid >> 7;
        const int pi = half*2 + sl;
        const int l0 = half*LH + sl*49;
        const float* p = P.a + ((size_t)(b*L_ + l0))*D_ + quad*4;
        ushort_t* q = P.a_b + ((size_t)(b*L_ + l0))*D_ + quad*4;
        float4 s = make_float4(0.f,0.f,0.f,0.f);
        for (int l=0;l<49;l++){
            float4 v = *(const float4*)(p + (size_t)l*D_);
            s.x += v.x; s.y += v.y; s.z += v.z; s.w += v.w;
            ushort_t r[4] = {f2b(v.x),f2b(v.y),f2b(v.z),f2b(v.w)};
            *(uint2*)(q + (size_t)l*D_) = *(uint2*)r;
        }
        *(float4*)(P.mcp + (size_t)pi*65536 + (size_t)b*D_ + quad*4) = s;
        return;
    }
    bid -= 256;
    if (bid < 8128){
        int ji = 0;
        while (bid >= P.j[ji].nblk){ bid -= P.j[ji].nblk; ji++; }
        const TJob jb = P.j[ji];
        int n0 = (bid % jb.nx)*32, k0 = (bid / jb.nx)*32;
        int tx = tid & 31, ty = tid >> 5;
        #pragma unroll
        for (int kk = ty; kk < 32; kk += 8){
            int k = k0 + kk, n = n0 + tx;
            float v = 0.f;
            if (k < jb.Ksz && n < jb.Nsz){
                v = jb.src[(size_t)k*jb.lds + n];
                if (jb.src2) v += jb.src2[(size_t)k*jb.lds + n];
            }
            t[kk][tx] = v;
        }
        __syncthreads();
        #pragma unroll
        for (int nn = ty; nn < 32; nn += 8){
            int n = n0 + nn, k = k0 + tx;
            if (k < jb.Ksz) jb.dst[(size_t)n*jb.ldk + jb.koff + k] = f2b(t[tx][nn]);
        }
        return;
    }
    bid -= 8128;
    if (bid == 0){
        for (int k = tid; k < G4H; k += 256) P.bias4h[k] = P.b_ih[k] + P.b_hh[k];
        P.bars[tid] = 0u;
        return;
    }
    bid -= 1;
    int i = bid*4 + (tid >> 6);
    int lane = tid & 63;
    int tt = i / B_, b = i - tt*B_;
    int cap = P.caps[b*T_ + tt];
    float4 v = ((const float4*)(P.embW + (size_t)cap*E_))[lane];
    ushort_t r[4] = {f2b(v.x),f2b(v.y),f2b(v.z),f2b(v.w)};
    *(uint2*)(P.xemb + (size_t)i*E_ + lane*4) = *(uint2*)r;
}

// h0: cvt to xcat + full hWp0 + zero hWp1 + beta-dot; grid B x 512
__global__ __launch_bounds__(512) void hw0cvt_k(const float* __restrict__ h0f,
                        const ushort_t* __restrict__ WhcT, const float* __restrict__ beta_W,
                        ushort_t* __restrict__ xcat, float* __restrict__ hWp, float* __restrict__ bdot){
    int b = blockIdx.x, tid = threadIdx.x;
    int lane = tid & 63, wave = tid >> 6;
    __shared__ ushort_t hls[512];
    __shared__ float rr[8];
    float hv = h0f[b*H_ + tid];
    ushort_t hb = f2b(hv);
    xcat[(size_t)b*KCAT + D_ + tid] = hb;
    hls[tid] = hb;
    hWp[(size_t)(b*2+1)*512 + tid] = 0.f;
    float dv = hv * beta_W[tid];
    #pragma unroll
    for (int off=32; off; off>>=1) dv += __shfl_down(dv, off);
    if (lane==0) rr[wave] = dv;
    __syncthreads();
    if (tid == 0){
        float s = rr[0]+rr[1]+rr[2]+rr[3]+rr[4]+rr[5]+rr[6]+rr[7];
        bdot[b*2] = s; bdot[b*2+1] = 0.f;
    }
    int wn = wave * 64;
    int col16 = lane & 15;
    int khi = (lane >> 4) * 8;
    bool a_on = (col16 == 0);
    f32x4 acc[4];
    #pragma unroll
    for (int f=0;f<4;f++) acc[f] = (f32x4){0.f,0.f,0.f,0.f};
    for (int kk=0; kk<16; kk++){
        bf16x8 af = (bf16x8){0,0,0,0,0,0,0,0};
        if (a_on) af = *(const bf16x8*)&hls[kk*32 + khi];
        #pragma unroll
        for (int f=0;f<4;f++){
            bf16x8 bf = *(const bf16x8*)(WhcT + (size_t)(wn + f*16 + col16)*512 + kk*32 + khi);
            acc[f] = __builtin_amdgcn_mfma_f32_16x16x32_bf16(af, bf, acc[f], 0, 0, 0);
        }
    }
    if (lane < 16){
        #pragma unroll
        for (int f=0;f<4;f++) hWp[(size_t)(b*2+0)*512 + wn + f*16 + lane] = acc[f][0];
    }
}

// ================= mega2 (1024 threads): lstm(t-1) + beta + hW-partial + attention(t) =================
// grid (B_, 2) x 1024; 2 pair-syncs per step via monotonic ebar[b]
__global__ __launch_bounds__(1024) void mega2_k(const ushort_t* __restrict__ wa,
                        const ushort_t* __restrict__ a_b,
                        const float* __restrict__ v,
                        const float* __restrict__ beta_W, const float* __restrict__ beta_b,
                        const ushort_t* __restrict__ WhcT,
                        const float* __restrict__ gp, const float* __restrict__ embWih,
                        float* __restrict__ cbuf, float* __restrict__ hWp,
                        ushort_t* __restrict__ xcat, ushort_t* __restrict__ Hall,
                        float* __restrict__ alphas_out, float* __restrict__ ebuf,
                        unsigned* __restrict__ ebar, float* __restrict__ bdot, int t)
{
    const int b = blockIdx.x, half = blockIdx.y;
    const int tid = threadIdx.x;                  // 0..1023, 16 waves
    const int lane = tid & 63, wave = tid >> 6;
    __shared__ ushort_t hls[256];
    __shared__ float red[32];
    __shared__ float al_s[224];
    __shared__ float4 part4[16][64];

    // ---- phase L: lstm for own j-half + beta partial + hW K-partial (skip at t==0) ----
    if (t > 0){
        float dv = 0.f;
        if (tid < 256){
            const int j = half*256 + tid;
            const float* eb = embWih + ((size_t)((t-1)*B_ + b))*G4H;
            float gi = eb[j], gf = eb[H_+j], gg = eb[2*H_+j], go = eb[3*H_+j];
            #pragma unroll
            for (int ks=0; ks<8; ks++){
                const float* g = gp + ((size_t)(ks*B_ + b))*G4H;
                gi += g[j]; gf += g[H_+j]; gg += g[2*H_+j]; go += g[3*H_+j];
            }
            float ig = sigmoidf_(gi), fg = sigmoidf_(gf);
            float g2 = fast_tanh(gg), og = sigmoidf_(go);
            float c = fg*cbuf[b*H_+j] + ig*g2;
            float h = og*fast_tanh(c);
            cbuf[b*H_+j] = c;
            ushort_t hb = f2b(h);
            xcat[(size_t)b*KCAT + D_ + j] = hb;
            Hall[((size_t)(t-1)*B_ + b)*H_ + j] = hb;
            hls[tid] = hb;
            dv = h * beta_W[j];
        }
        #pragma unroll
        for (int off=32; off; off>>=1) dv += __shfl_down(dv, off);
        if (lane==0) red[wave] = dv;
        __syncthreads();
        // hWp[half] = h_half @ Whc[half*256 : half*256+256, :]  (16 waves x 32 cols)
        int wn = wave * 32;
        int col16 = lane & 15;
        int khi = (lane >> 4) * 8;
        bool a_on = (col16 == 0);
        f32x4 acc[2];
        acc[0] = (f32x4){0.f,0.f,0.f,0.f};
        acc[1] = (f32x4){0.f,0.f,0.f,0.f};
        #pragma unroll
        for (int kk=0; kk<8; kk++){
            bf16x8 af = (bf16x8){0,0,0,0,0,0,0,0};
            if (a_on) af = *(const bf16x8*)&hls[kk*32 + khi];
            #pragma unroll
            for (int f=0;f<2;f++){
                bf16x8 bf = *(const bf16x8*)(WhcT + (size_t)(wn + f*16 + col16)*512 + half*256 + kk*32 + khi);
                acc[f] = __builtin_amdgcn_mfma_f32_16x16x32_bf16(af, bf, acc[f], 0, 0, 0);
            }
        }
        if (lane < 16){
            #pragma unroll
            for (int f=0;f<2;f++) hWp[(size_t)(b*2+half)*512 + wn + f*16 + lane] = acc[f][0];
        }
    }
    // ---- pair sync 1: h + hWp + bdot complete for both halves ----
    __syncthreads();
    if (tid == 0){
        if (t > 0){
            float s = 0.f;
            #pragma unroll
            for (int w=0; w<16; w++) s += red[w];
            bdot[b*2+half] = s;
        }
        __threadfence();
        atomicAdd(&ebar[b], 1u);
        const unsigned tgt = 2u*(unsigned)(2*t+1);
        while (__hip_atomic_load(&ebar[b], __ATOMIC_ACQUIRE, __HIP_MEMORY_SCOPE_AGENT) < tgt)
            __builtin_amdgcn_s_sleep(1);
    }
    __syncthreads();
    // ---- phase E: e over own l-half (16 waves) ----
    {
        const float* hp0 = hWp + (size_t)(b*2+0)*512 + lane*8;
        const float* hp1 = hWp + (size_t)(b*2+1)*512 + lane*8;
        float4 p00 = *(const float4*)hp0, p01 = *(const float4*)(hp0+4);
        float4 p10 = *(const float4*)hp1, p11 = *(const float4*)(hp1+4);
        float4 hw0 = make_float4(p00.x+p10.x, p00.y+p10.y, p00.z+p10.z, p00.w+p10.w);
        float4 hw1 = make_float4(p01.x+p11.x, p01.y+p11.y, p01.z+p11.z, p01.w+p11.w);
        const float* vp = v + lane*8;
        float4 v0 = *(const float4*)vp, v1 = *(const float4*)(vp+4);
        const int l0 = half*LH;
        for (int r = wave; r < LH; r += 16){
            int4 raw = *(const int4*)(wa + (((size_t)(b*L_ + l0 + r))<<9) + lane*8);
            const unsigned* u = (const unsigned*)&raw;
            float s;
            s  = fast_tanh(b2f_lo(u[0]) + hw0.x)*v0.x;
            s += fast_tanh(b2f_hi(u[0]) + hw0.y)*v0.y;
            s += fast_tanh(b2f_lo(u[1]) + hw0.z)*v0.z;
            s += fast_tanh(b2f_hi(u[1]) + hw0.w)*v0.w;
            s += fast_tanh(b2f_lo(u[2]) + hw1.x)*v1.x;
            s += fast_tanh(b2f_hi(u[2]) + hw1.y)*v1.y;
            s += fast_tanh(b2f_lo(u[3]) + hw1.z)*v1.z;
            s += fast_tanh(b2f_hi(u[3]) + hw1.w)*v1.w;
            #pragma unroll
            for (int off=32; off; off>>=1) s += __shfl_down(s, off);
            if (lane==0) ebuf[b*L_ + l0 + r] = s;
        }
    }
    // ---- pair sync 2: e complete ----
    __syncthreads();
    if (tid == 0){
        __threadfence();
        atomicAdd(&ebar[b], 1u);
        const unsigned tgt = 2u*(unsigned)(2*t+2);
        while (__hip_atomic_load(&ebar[b], __ATOMIC_ACQUIRE, __HIP_MEMORY_SCOPE_AGENT) < tgt)
            __builtin_amdgcn_s_sleep(1);
    }
    __syncthreads();
    // ---- softmax over all 196: wave-level reduces (16 waves) ----
    float ev = (tid < L_) ? ebuf[b*L_ + tid] : -3.0e38f;
    float wmax = ev;
    #pragma unroll
    for (int off=32; off; off>>=1) wmax = fmaxf(wmax, __shfl_down(wmax, off));
    if (lane==0) red[wave] = wmax;
    __syncthreads();
    float m = red[0];
    #pragma unroll
    for (int w=1; w<16; w++) m = fmaxf(m, red[w]);
    float pr = (tid < L_) ? __expf(ev - m) : 0.f;
    float wsum = pr;
    #pragma unroll
    for (int off=32; off; off>>=1) wsum += __shfl_down(wsum, off);
    if (lane==0) red[16+wave] = wsum;
    __syncthreads();
    float sum = red[16];
    #pragma unroll
    for (int w=1; w<16; w++) sum += red[16+w];
    float inv = 1.f / sum;
    if (tid < L_) al_s[tid] = pr*inv;
    const int l0 = half*LH;
    if (tid >= l0 && tid < l0 + LH)
        __builtin_nontemporal_store(pr*inv, alphas_out + (size_t)b*TM1*L_ + (size_t)t*L_ + tid);
    __syncthreads();
    // ---- ctx: 256 d's per block, 4 d's per thread (uint2), 16-way l split ----
    {
        const int dg = tid & 63;
        const int lr = tid >> 6;            // 0..15
        const int d0 = half*256 + dg*4;
        const ushort_t* pa = a_b + (((size_t)(b*L_))<<9) + d0;
        float4 s = make_float4(0.f,0.f,0.f,0.f);
        for (int l = lr; l < L_; l += 16){
            uint2 av = *(const uint2*)(pa + ((size_t)l<<9));
            float al = al_s[l];
            s.x = fmaf(al, b2f_lo(av.x), s.x);
            s.y = fmaf(al, b2f_hi(av.x), s.y);
            s.z = fmaf(al, b2f_lo(av.y), s.z);
            s.w = fmaf(al, b2f_hi(av.y), s.w);
        }
        part4[lr][dg] = s;
        __syncthreads();
        if (tid < 64){
            float beta = sigmoidf_(bdot[b*2] + bdot[b*2+1] + beta_b[0]);
            float4 r = make_float4(0.f,0.f,0.f,0.f);
            #pragma unroll
            for (int q=0;q<16;q++){
                float4 pv = part4[q][tid];
                r.x += pv.x; r.y += pv.y; r.z += pv.z; r.w += pv.w;
            }
            unsigned lo = (unsigned)f2b(beta*r.x) | (((unsigned)f2b(beta*r.y))<<16);
            unsigned hi = (unsigned)f2b(beta*r.z) | (((unsigned)f2b(beta*r.w))<<16);
            uint2 pk; pk.x = lo; pk.y = hi;
            *(uint2*)(xcat + (size_t)b*KCAT + half*256 + tid*4) = pk;
        }
    }
}

// gates partials: grid (32, 8) x 256; tile M128 x N64, K-chunk 128
__global__ __launch_bounds__(256) void gates_k(const ushort_t* __restrict__ xcat,
                        const ushort_t* __restrict__ WcatT, float* __restrict__ gp){
    __shared__ ushort_t As[128*32];
    __shared__ ushort_t Bs[64*32];
    const int bn = blockIdx.x*64;
    const int ks = blockIdx.y;
    const int tid = threadIdx.x;
    const int lane = tid & 63, wave = tid >> 6;
    const int wm = wave*32;
    const int lrow = lane & 15;
    const int lk8 = (lane >> 4) * 8;
    f32x4 acc[2][4];
    #pragma unroll
    for (int i=0;i<2;i++)
        #pragma unroll
        for (int j=0;j<4;j++) acc[i][j] = (f32x4){0.f,0.f,0.f,0.f};

    for (int kk = 0; kk < 4; ++kk){
        int k0 = ks*128 + kk*32;
        int c0 = 2*tid;
        int r0 = c0 >> 2,  kq0 = (c0 & 3)*8;
        int r1 = (c0+1) >> 2, kq1 = ((c0+1) & 3)*8;
        int4 a0 = *(const int4*)(xcat + (size_t)r0*KCAT + k0 + kq0);
        int4 a1 = *(const int4*)(xcat + (size_t)r1*KCAT + k0 + kq1);
        int rb = tid >> 2, kqb = (tid & 3)*8;
        int4 b0 = *(const int4*)(WcatT + (size_t)(bn+rb)*KCAT + k0 + kqb);
        __syncthreads();
        *(int4*)&As[r0*32 + kq0] = a0;
        *(int4*)&As[r1*32 + kq1] = a1;
        *(int4*)&Bs[rb*32 + kqb] = b0;
        __syncthreads();
        bf16x8 af[2], bfr[4];
        #pragma unroll
        for (int i=0;i<2;i++) af[i] = *(bf16x8*)&As[(wm + i*16 + lrow)*32 + lk8];
        #pragma unroll
        for (int j=0;j<4;j++) bfr[j] = *(bf16x8*)&Bs[(j*16 + lrow)*32 + lk8];
        #pragma unroll
        for (int i=0;i<2;i++)
            #pragma unroll
            for (int j=0;j<4;j++)
                acc[i][j] = __builtin_amdgcn_mfma_f32_16x16x32_bf16(af[i], bfr[j], acc[i][j], 0, 0, 0);
    }
    const int rq = (lane >> 4) * 4;
    #pragma unroll
    for (int i=0;i<2;i++){
        #pragma unroll
        for (int j=0;j<4;j++){
            int gcol = bn + j*16 + lrow;
            #pragma unroll
            for (int q=0;q<4;q++){
                int grow = wm + i*16 + rq + q;
                gp[((size_t)(ks*B_ + grow))*G4H + gcol] = acc[i][j][q];
            }
        }
    }
}

// final lstm (h_19 -> Hall[18]); grid B x 512
__global__ __launch_bounds__(512) void lstmfin_k(const float* __restrict__ gp, const float* __restrict__ embWih,
                       const float* __restrict__ cbuf, ushort_t* __restrict__ Hall){
    int b = blockIdx.x, j = threadIdx.x;
    const float* eb = embWih + ((size_t)(18*B_ + b))*G4H;
    float gi = eb[j], gf = eb[H_+j], gg = eb[2*H_+j], go = eb[3*H_+j];
    #pragma unroll
    for (int ks=0; ks<8; ks++){
        const float* g = gp + ((size_t)(ks*B_ + b))*G4H;
        gi += g[j]; gf += g[H_+j]; gg += g[2*H_+j]; go += g[3*H_+j];
    }
    float ig = sigmoidf_(gi), fg = sigmoidf_(gf);
    float g2 = fast_tanh(gg), og = sigmoidf_(go);
    float c = fg*cbuf[b*H_+j] + ig*g2;
    float h = og*fast_tanh(c);
    Hall[((size_t)18*B_ + b)*H_ + j] = f2b(h);
}

extern "C" void kernel_launch(void* const* d_in, const int* in_sizes, int n_in,
                              void* d_out, int out_size, void* d_ws, size_t ws_size,
                              hipStream_t stream) {
    const float* a      = (const float*)d_in[0];
    const int*   caps   = (const int*)  d_in[1];
    const float* embW   = (const float*)d_in[3];
    const float* Wa     = (const float*)d_in[4];
    const float* Wh     = (const float*)d_in[5];
    const float* Wc     = (const float*)d_in[6];
    const float* v      = (const float*)d_in[7];
    const float* beta_W = (const float*)d_in[8];
    const float* beta_b = (const float*)d_in[9];
    const float* W_ih   = (const float*)d_in[10];
    const float* W_hh   = (const float*)d_in[11];
    const float* b_ih   = (const float*)d_in[12];
    const float* b_hh   = (const float*)d_in[13];
    const float* fc_W   = (const float*)d_in[14];
    const float* fc_b   = (const float*)d_in[15];
    const float* iWh    = (const float*)d_in[16];
    const float* ibh    = (const float*)d_in[17];
    const float* iWc    = (const float*)d_in[18];
    const float* ibc    = (const float*)d_in[19];

    float* out    = (float*)d_out;
    float* alphas = out + (size_t)ROWS*V_;

    // d_out scratch (dead before final logits GEMM overwrites it)
    char* ob = (char*)d_out;
    ushort_t* wa_b   = (ushort_t*)(ob);               // 25,690,112 B
    ushort_t* a_b    = (ushort_t*)(ob + 25690112);    // 25,690,112 B
    float*    embWih = (float*)   (ob + 51380224);    // 19,922,944 B

    // d_ws layout (byte offsets)
    char* wb = (char*)d_ws;
    float* mcp      = (float*)(wb);              // 1,048,576
    float* bdot     = (float*)(wb + 1048576);    // 4096
    float* cbuf     = (float*)(wb + 1052672);    // 262144
    float* h0f      = (float*)(wb + 1314816);    // 262144
    float* hWp      = (float*)(wb + 1576960);    // 524288
    float* ebuf     = (float*)(wb + 2101248);    // 102400
    float* bias4h   = (float*)(wb + 2203648);    // 8192
    unsigned* bars  = (unsigned*)(wb + 2211840); // 4096: ebar[0..127]
    float* gp       = (float*)(wb + 2215936);    // 8388608
    ushort_t* xcat_b = (ushort_t*)(wb + 10604544);  // 262144
    ushort_t* xemb_b = (ushort_t*)(wb + 10866688);  // 1245184
    ushort_t* Hall   = (ushort_t*)(wb + 12111872);  // 2490368
    ushort_t* WaT    = (ushort_t*)(wb + 14602240);  // 524288
    ushort_t* WhcT   = (ushort_t*)(wb + 15126528);  // 524288
    ushort_t* WihT   = (ushort_t*)(wb + 15650816);  // 1048576
    ushort_t* WcatT  = (ushort_t*)(wb + 16699392);  // 4194304
    ushort_t* fcWT   = (ushort_t*)(wb + 20893696);  // 10354688 -> ends ~29.8MB

    // ---- prep (1 launch; mean blocks first so they overlap the transposes) ----
    PrepArgs P;
    P.j[0] = { Wa,   nullptr, WaT,  512, 512, 512,  0,   512,  16, 256 };
    P.j[1] = { Wh,   Wc,      WhcT, 512, 512, 512,  0,   512,  16, 256 };
    P.j[2] = { W_ih, nullptr, WihT, G4H, 256, G4H,  0,   256,  64, 512 };
    P.j[3] = { W_ih + (size_t)E_*G4H, nullptr, WcatT, G4H, 512, G4H, 0,   KCAT, 64, 1024 };
    P.j[4] = { W_hh, nullptr, WcatT, G4H, 512, G4H,  512, KCAT, 64, 1024 };
    P.j[5] = { fc_W, nullptr, fcWT, V_,  512, V_,   0,   512,  316, 5056 };
    P.a = a; P.a_b = a_b; P.mcp = mcp;
    P.b_ih = b_ih; P.b_hh = b_hh; P.bias4h = bias4h; P.bars = bars;
    P.caps = caps; P.embW = embW; P.xemb = xemb_b;
    prep_all_k<<<8993, 256, 0, stream>>>(P);

    gemm64t2<<<dim3(8,2,2), 256, 0, stream>>>(mcp, D_, iWh, iWc, H_, h0f, cbuf, H_, ibh, ibc);
    hw0cvt_k<<<B_, 512, 0, stream>>>(h0f, WhcT, beta_W, xcat_b, hWp, bdot);

    // wa_b + embWih in one dispatch
    GJob g0 = { a_b,    512, WaT,  512, wa_b,   512, 512,  512, nullptr, 1, 4,  784 };
    GJob g1 = { xemb_b, 256, WihT, 256, embWih, G4H, G4H,  256, bias4h,  0, 16, 304 };
    gemm_dual_k<<<1088, 256, 0, stream>>>(g0, g1);

    // ---- loop: 2 kernels/step ----
    for (int t = 0; t < TM1; ++t){
        mega2_k<<<dim3(B_,2), 1024, 0, stream>>>(wa_b, a_b, v, beta_W, beta_b, WhcT,
                                                 gp, embWih, cbuf, hWp, xcat_b, Hall,
                                                 alphas, ebuf, bars, bdot, t);
        gates_k<<<dim3(32,8), 256, 0, stream>>>(xcat_b, WcatT, gp);
    }
    lstmfin_k<<<B_, 512, 0, stream>>>(gp, embWih, cbuf, Hall);

    // logits = Hall @ fc_W + fc_b   (2432 x 10000 x 512)
    gemm_logits_k<<<dim3(1520), 256, 0, stream>>>(Hall, H_, fcWT, H_, out, V_, V_, H_, fc_b);
}

// Round 16
// 966.881 us; speedup vs baseline: 1.4888x; 1.0109x over previous
//
#include <hip/hip_runtime.h>
#include <hip/hip_bf16.h>
#include <math.h>

#define B_ 128
#define L_ 196
#define D_ 512
#define T_ 20
#define V_ 10000
#define E_ 256
#define H_ 512
#define A_ 512
#define TM1 19
#define ROWS (TM1*B_)      /* 2432 */
#define G4H 2048
#define KCAT 1024
#define LH 98

typedef unsigned short ushort_t;
typedef __attribute__((ext_vector_type(8))) short bf16x8;
typedef __attribute__((ext_vector_type(4))) float f32x4;

__device__ __forceinline__ float fast_tanh(float x){
    float ax = fabsf(x);
    float e = __expf(-2.f*ax);
    float r = __builtin_amdgcn_rcpf(1.f + e);
    return copysignf((1.f - e)*r, x);
}
__device__ __forceinline__ float sigmoidf_(float x){
    return __builtin_amdgcn_rcpf(1.f + __expf(-x));
}
__device__ __forceinline__ ushort_t f2b(float f){
    union{float f; unsigned u;} x; x.f = f;
    unsigned r = x.u + 0x7fffu + ((x.u>>16)&1u);
    return (ushort_t)(r>>16);
}
__device__ __forceinline__ float b2f(ushort_t h){
    union{unsigned u; float f;} x; x.u = ((unsigned)h)<<16;
    return x.f;
}
__device__ __forceinline__ float b2f_lo(unsigned u){ union{unsigned u; float f;} x; x.u = u<<16; return x.f; }
__device__ __forceinline__ float b2f_hi(unsigned u){ union{unsigned u; float f;} x; x.u = u & 0xffff0000u; return x.f; }

#define GL16(gsrc, ldst) __builtin_amdgcn_global_load_lds( \
    (const __attribute__((address_space(1))) unsigned*)(gsrc), \
    (__attribute__((address_space(3))) unsigned*)(ldst), 16, 0, 0)

// ========== logits GEMM: dbuf global_load_lds + XCD swizzle + LDS-coalesced NT epilogue ==========
__global__ __launch_bounds__(256)
void gemm_logits_k(const ushort_t* __restrict__ A, int lda,
                   const ushort_t* __restrict__ BT, int ldb,
                   float* __restrict__ C, int ldc,
                   int N, int K, const float* __restrict__ bias)
{
    __shared__ ushort_t As[2][4096];
    __shared__ ushort_t Bs[2][4096];
    int bid = blockIdx.x;
    int swz = (bid & 7)*190 + (bid >> 3);
    int mt = swz % 19, nt = swz / 19;
    if (nt >= 79) return;
    const int bm = mt*128, bn = nt*128;
    const int tid = threadIdx.x;
    const int lane = tid & 63;
    const int wave = tid >> 6;
    const int wm = (wave >> 1) * 64;
    const int wn = (wave & 1) * 64;
    const int lrow = lane & 15;
    const int lk8  = (lane >> 4) * 8;
    const int srow = tid >> 2;
    const int skq0 = (tid & 3) * 8;
    const int wbase = wave * 512;

    f32x4 acc[4][4];
    #pragma unroll
    for (int i=0;i<4;i++)
        #pragma unroll
        for (int j=0;j<4;j++) acc[i][j] = (f32x4){0.f,0.f,0.f,0.f};

    const ushort_t* Ab = A  + (size_t)(bm+srow)*lda + skq0;
    const ushort_t* Bb = BT + (size_t)(bn+srow)*ldb + skq0;

    GL16(Ab,                    &As[0][wbase]);
    GL16(Ab + (size_t)64*lda,   &As[0][2048 + wbase]);
    GL16(Bb,                    &Bs[0][wbase]);
    GL16(Bb + (size_t)64*ldb,   &Bs[0][2048 + wbase]);

    int buf = 0;
    for (int k0 = 0; k0 < K; k0 += 32) {
        asm volatile("s_waitcnt vmcnt(0)" ::: "memory");
        __syncthreads();
        if (k0 + 32 < K){
            int nb = buf ^ 1;
            GL16(Ab + k0 + 32,                  &As[nb][wbase]);
            GL16(Ab + (size_t)64*lda + k0 + 32, &As[nb][2048 + wbase]);
            GL16(Bb + k0 + 32,                  &Bs[nb][wbase]);
            GL16(Bb + (size_t)64*ldb + k0 + 32, &Bs[nb][2048 + wbase]);
        }
        bf16x8 af[4], bfr[4];
        #pragma unroll
        for (int i=0;i<4;i++) af[i]  = *(bf16x8*)&As[buf][(wm + i*16 + lrow)*32 + lk8];
        #pragma unroll
        for (int j=0;j<4;j++) bfr[j] = *(bf16x8*)&Bs[buf][(wn + j*16 + lrow)*32 + lk8];
        #pragma unroll
        for (int i=0;i<4;i++)
            #pragma unroll
            for (int j=0;j<4;j++)
                acc[i][j] = __builtin_amdgcn_mfma_f32_16x16x32_bf16(af[i], bfr[j], acc[i][j], 0, 0, 0);
        buf ^= 1;
    }

    // epilogue: stage 32x128 f32 chunks in LDS, coalesced NT float4 stores
    const int rq = (lane >> 4) * 4;
    float* eps = (float*)As;
    #pragma unroll
    for (int c = 0; c < 4; ++c){
        __syncthreads();
        if ((wave >> 1) == (c >> 1)){
            const int ib = 2*(c & 1);
            #pragma unroll
            for (int ii = 0; ii < 2; ++ii){
                #pragma unroll
                for (int j = 0; j < 4; ++j){
                    #pragma unroll
                    for (int q = 0; q < 4; ++q){
                        int lr_ = ii*16 + rq + q;
                        int lc  = wn + j*16 + lrow;
                        eps[lr_*128 + lc] = acc[ib+ii][j][q];
                    }
                }
            }
        }
        __syncthreads();
        for (int it = tid; it < 1024; it += 256){
            int r = it >> 5, c4 = it & 31;
            int col0 = bn + c4*4;
            if (col0 >= N) continue;
            f32x4 vv = *(f32x4*)&eps[r*128 + c4*4];
            float* dst = &C[(size_t)(bm + 32*c + r)*ldc + col0];
            if (col0 + 3 < N){
                float4 bb = *(const float4*)(bias + col0);
                vv[0] += bb.x; vv[1] += bb.y; vv[2] += bb.z; vv[3] += bb.w;
                __builtin_nontemporal_store(vv, (f32x4*)dst);
            } else {
                for (int e=0; e<4 && col0+e < N; ++e)
                    __builtin_nontemporal_store(vv[e] + bias[col0+e], dst + e);
            }
        }
    }
}

// ================= dual GEMM (wa + embWih in one dispatch), runtime job =================
struct GJob { const ushort_t* A; int lda; const ushort_t* BT; int ldb;
              void* C; int ldc; int N, K; const float* bias; int out_bf16; int nx; int nblk; };

__global__ __launch_bounds__(256) void gemm_dual_k(GJob j0, GJob j1){
    __shared__ ushort_t As[2][4096];
    __shared__ ushort_t Bs[2][4096];
    int bid = blockIdx.x;
    GJob jb = (bid < j0.nblk) ? j0 : j1;
    if (bid >= j0.nblk) bid -= j0.nblk;
    const int bn = (bid % jb.nx)*128, bm = (bid / jb.nx)*128;
    const int tid = threadIdx.x;
    const int lane = tid & 63;
    const int wave = tid >> 6;
    const int wm = (wave >> 1) * 64;
    const int wn = (wave & 1) * 64;
    const int lrow = lane & 15;
    const int lk8  = (lane >> 4) * 8;
    const int srow = tid >> 2;
    const int skq0 = (tid & 3) * 8;
    const int wbase = wave * 512;

    f32x4 acc[4][4];
    #pragma unroll
    for (int i=0;i<4;i++)
        #pragma unroll
        for (int j=0;j<4;j++) acc[i][j] = (f32x4){0.f,0.f,0.f,0.f};

    const ushort_t* Ab = jb.A  + (size_t)(bm+srow)*jb.lda + skq0;
    const ushort_t* Bb = jb.BT + (size_t)(bn+srow)*jb.ldb + skq0;

    GL16(Ab,                        &As[0][wbase]);
    GL16(Ab + (size_t)64*jb.lda,    &As[0][2048 + wbase]);
    GL16(Bb,                        &Bs[0][wbase]);
    GL16(Bb + (size_t)64*jb.ldb,    &Bs[0][2048 + wbase]);

    int buf = 0;
    for (int k0 = 0; k0 < jb.K; k0 += 32) {
        asm volatile("s_waitcnt vmcnt(0)" ::: "memory");
        __syncthreads();
        if (k0 + 32 < jb.K){
            int nb = buf ^ 1;
            GL16(Ab + k0 + 32,                      &As[nb][wbase]);
            GL16(Ab + (size_t)64*jb.lda + k0 + 32,  &As[nb][2048 + wbase]);
            GL16(Bb + k0 + 32,                      &Bs[nb][wbase]);
            GL16(Bb + (size_t)64*jb.ldb + k0 + 32,  &Bs[nb][2048 + wbase]);
        }
        bf16x8 af[4], bfr[4];
        #pragma unroll
        for (int i=0;i<4;i++) af[i]  = *(bf16x8*)&As[buf][(wm + i*16 + lrow)*32 + lk8];
        #pragma unroll
        for (int j=0;j<4;j++) bfr[j] = *(bf16x8*)&Bs[buf][(wn + j*16 + lrow)*32 + lk8];
        #pragma unroll
        for (int i=0;i<4;i++)
            #pragma unroll
            for (int j=0;j<4;j++)
                acc[i][j] = __builtin_amdgcn_mfma_f32_16x16x32_bf16(af[i], bfr[j], acc[i][j], 0, 0, 0);
        buf ^= 1;
    }

    const int rq = (lane >> 4) * 4;
    #pragma unroll
    for (int j=0;j<4;j++){
        int col = bn + wn + j*16 + lrow;
        if (col >= jb.N) continue;
        float bv = jb.bias ? jb.bias[col] : 0.f;
        #pragma unroll
        for (int i=0;i<4;i++){
            #pragma unroll
            for (int q=0;q<4;q++){
                int row = bm + wm + i*16 + rq + q;
                float v = acc[i][j][q] + bv;
                if (jb.out_bf16) ((ushort_t*)jb.C)[(size_t)row*jb.ldc + col] = f2b(v);
                else             ((float*)jb.C)[(size_t)row*jb.ldc + col] = v;
            }
        }
    }
}

// ===== f32 tile GEMM (init path): C = tanh((Σ mcp partials)/L @ B + bias), z picks job =====
__global__ __launch_bounds__(256) void gemm64t2(const float* __restrict__ Amcp, int lda,
                       const float* __restrict__ B0, const float* __restrict__ B1, int ldb,
                       float* __restrict__ C0, float* __restrict__ C1, int ldc,
                       const float* __restrict__ bias0, const float* __restrict__ bias1)
{
    const float* Bm  = blockIdx.z ? B1 : B0;
    float* C         = blockIdx.z ? C1 : C0;
    const float* bias= blockIdx.z ? bias1 : bias0;
    __shared__ float As[16][65];
    __shared__ float Bs[16][65];
    int bm = blockIdx.y*64, bn = blockIdx.x*64;
    int tid = threadIdx.x;
    int tx = tid & 15, ty = tid >> 4;
    const float invL = 1.f/(float)L_;
    float acc[4][4] = {};
    for (int k0 = 0; k0 < D_; k0 += 16) {
        {
            int r  = tid >> 2;
            int kq = (tid & 3) * 4;
            const float* Ap = Amcp + (size_t)(bm+r)*lda + k0 + kq;
            float4 v0 = *(const float4*)(Ap);
            float4 v1 = *(const float4*)(Ap + 65536);
            float4 v2 = *(const float4*)(Ap + 131072);
            float4 v3 = *(const float4*)(Ap + 196608);
            float4 va = make_float4((v0.x+v1.x+v2.x+v3.x)*invL, (v0.y+v1.y+v2.y+v3.y)*invL,
                                    (v0.z+v1.z+v2.z+v3.z)*invL, (v0.w+v1.w+v2.w+v3.w)*invL);
            As[kq+0][r]=va.x; As[kq+1][r]=va.y; As[kq+2][r]=va.z; As[kq+3][r]=va.w;
        }
        {
            int kk = tid >> 4;
            int nq = (tid & 15) * 4;
            float4 vb = *(const float4*)(Bm + (size_t)(k0+kk)*ldb + bn + nq);
            Bs[kk][nq+0]=vb.x; Bs[kk][nq+1]=vb.y; Bs[kk][nq+2]=vb.z; Bs[kk][nq+3]=vb.w;
        }
        __syncthreads();
        #pragma unroll
        for (int k = 0; k < 16; ++k) {
            float a0[4], b0[4];
            #pragma unroll
            for (int i=0;i<4;i++) a0[i] = As[k][ty*4+i];
            #pragma unroll
            for (int j=0;j<4;j++) b0[j] = Bs[k][tx*4+j];
            #pragma unroll
            for (int i=0;i<4;i++)
                #pragma unroll
                for (int j=0;j<4;j++)
                    acc[i][j] = fmaf(a0[i], b0[j], acc[i][j]);
        }
        __syncthreads();
    }
    #pragma unroll
    for (int i=0;i<4;i++){
        int row = bm + ty*4 + i;
        #pragma unroll
        for (int j=0;j<4;j++){
            int col = bn + tx*4 + j;
            C[(size_t)row*ldc + col] = fast_tanh(acc[i][j] + bias[col]);
        }
    }
}

// ================= fused prep: mean/cvt FIRST + 6 transposes + bias/bars + emb gather =================
struct TJob { const float* src; const float* src2; ushort_t* dst;
              int lds, Ksz, Nsz, koff, ldk, nx, nblk; };
struct PrepArgs {
    TJob j[6];
    const float* a; ushort_t* a_b; float* mcp;
    const float* b_ih; const float* b_hh; float* bias4h; unsigned* bars;
    const int* caps; const float* embW; ushort_t* xemb;
};

__global__ __launch_bounds__(256) void prep_all_k(PrepArgs P){
    __shared__ float t[32][33];
    int bid = blockIdx.x;
    const int tid = threadIdx.x;
    if (bid < 256){
        const int b = bid >> 1, half = bid & 1;
        const int quad = tid & 127;
        const int sl = tid >> 7;
        const int pi = half*2 + sl;
        const int l0 = half*LH + sl*49;
        const float* p = P.a + ((size_t)(b*L_ + l0))*D_ + quad*4;
        ushort_t* q = P.a_b + ((size_t)(b*L_ + l0))*D_ + quad*4;
        float4 s = make_float4(0.f,0.f,0.f,0.f);
        for (int l=0;l<49;l++){
            float4 v = *(const float4*)(p + (size_t)l*D_);
            s.x += v.x; s.y += v.y; s.z += v.z; s.w += v.w;
            ushort_t r[4] = {f2b(v.x),f2b(v.y),f2b(v.z),f2b(v.w)};
            *(uint2*)(q + (size_t)l*D_) = *(uint2*)r;
        }
        *(float4*)(P.mcp + (size_t)pi*65536 + (size_t)b*D_ + quad*4) = s;
        return;
    }
    bid -= 256;
    if (bid < 8128){
        int ji = 0;
        while (bid >= P.j[ji].nblk){ bid -= P.j[ji].nblk; ji++; }
        const TJob jb = P.j[ji];
        int n0 = (bid % jb.nx)*32, k0 = (bid / jb.nx)*32;
        int tx = tid & 31, ty = tid >> 5;
        #pragma unroll
        for (int kk = ty; kk < 32; kk += 8){
            int k = k0 + kk, n = n0 + tx;
            float v = 0.f;
            if (k < jb.Ksz && n < jb.Nsz){
                v = jb.src[(size_t)k*jb.lds + n];
                if (jb.src2) v += jb.src2[(size_t)k*jb.lds + n];
            }
            t[kk][tx] = v;
        }
        __syncthreads();
        #pragma unroll
        for (int nn = ty; nn < 32; nn += 8){
            int n = n0 + nn, k = k0 + tx;
            if (k < jb.Ksz) jb.dst[(size_t)n*jb.ldk + jb.koff + k] = f2b(t[tx][nn]);
        }
        return;
    }
    bid -= 8128;
    if (bid == 0){
        for (int k = tid; k < G4H; k += 256) P.bias4h[k] = P.b_ih[k] + P.b_hh[k];
        P.bars[tid] = 0u;
        return;
    }
    bid -= 1;
    int i = bid*4 + (tid >> 6);
    int lane = tid & 63;
    int tt = i / B_, b = i - tt*B_;
    int cap = P.caps[b*T_ + tt];
    float4 v = ((const float4*)(P.embW + (size_t)cap*E_))[lane];
    ushort_t r[4] = {f2b(v.x),f2b(v.y),f2b(v.z),f2b(v.w)};
    *(uint2*)(P.xemb + (size_t)i*E_ + lane*4) = *(uint2*)r;
}

// h0: cvt to xcat + full hW0 + beta-dot; grid B x 512
__global__ __launch_bounds__(512) void hw0cvt_k(const float* __restrict__ h0f,
                        const ushort_t* __restrict__ WhcT, const float* __restrict__ beta_W,
                        ushort_t* __restrict__ xcat, float* __restrict__ hW0, float* __restrict__ bdot0){
    int b = blockIdx.x, tid = threadIdx.x;
    int lane = tid & 63, wave = tid >> 6;
    __shared__ ushort_t hls[512];
    __shared__ float rr[8];
    float hv = h0f[b*H_ + tid];
    ushort_t hb = f2b(hv);
    xcat[(size_t)b*KCAT + D_ + tid] = hb;
    hls[tid] = hb;
    float dv = hv * beta_W[tid];
    #pragma unroll
    for (int off=32; off; off>>=1) dv += __shfl_down(dv, off);
    if (lane==0) rr[wave] = dv;
    __syncthreads();
    if (tid == 0)
        bdot0[b] = rr[0]+rr[1]+rr[2]+rr[3]+rr[4]+rr[5]+rr[6]+rr[7];
    int wn = wave * 64;
    int col16 = lane & 15;
    int khi = (lane >> 4) * 8;
    bool a_on = (col16 == 0);
    f32x4 acc[4];
    #pragma unroll
    for (int f=0;f<4;f++) acc[f] = (f32x4){0.f,0.f,0.f,0.f};
    for (int kk=0; kk<16; kk++){
        bf16x8 af = (bf16x8){0,0,0,0,0,0,0,0};
        if (a_on) af = *(const bf16x8*)&hls[kk*32 + khi];
        #pragma unroll
        for (int f=0;f<4;f++){
            bf16x8 bf = *(const bf16x8*)(WhcT + (size_t)(wn + f*16 + col16)*512 + kk*32 + khi);
            acc[f] = __builtin_amdgcn_mfma_f32_16x16x32_bf16(af, bf, acc[f], 0, 0, 0);
        }
    }
    if (lane < 16){
        #pragma unroll
        for (int f=0;f<4;f++) hW0[(size_t)b*512 + wn + f*16 + lane] = acc[f][0];
    }
}

// ====== mega2 (1024 thr): full-duplicated lstm(t-1) + local hW -> e -> 1 pair-sync -> softmax/ctx ======
// grid (B_, 2) x 1024; ONE pair-sync per step (e-exchange) via monotonic ebar[b]
__global__ __launch_bounds__(1024) void mega2_k(const ushort_t* __restrict__ wa,
                        const ushort_t* __restrict__ a_b,
                        const float* __restrict__ v,
                        const float* __restrict__ beta_W, const float* __restrict__ beta_b,
                        const ushort_t* __restrict__ WhcT,
                        const float* __restrict__ gp, const float* __restrict__ embWih,
                        float* __restrict__ cbuf2, const float* __restrict__ hW0,
                        const float* __restrict__ bdot0,
                        ushort_t* __restrict__ xcat, ushort_t* __restrict__ Hall,
                        float* __restrict__ alphas_out, float* __restrict__ ebuf,
                        unsigned* __restrict__ ebar, int t)
{
    const int b = blockIdx.x, half = blockIdx.y;
    const int tid = threadIdx.x;                  // 0..1023, 16 waves
    const int lane = tid & 63, wave = tid >> 6;
    __shared__ ushort_t hls[512];
    __shared__ float hWl[512];
    __shared__ float red[32];
    __shared__ float al_s[224];
    __shared__ float e_s[LH];
    __shared__ float bdot_s;
    __shared__ float4 part4[16][64];

    // ---- phase L: FULL lstm (duplicated across pair) + beta dot + FULL hW into LDS ----
    if (t > 0){
        float dv = 0.f;
        if (tid < 512){
            const int j = tid;
            const float* eb = embWih + ((size_t)((t-1)*B_ + b))*G4H;
            float gi = eb[j], gf = eb[H_+j], gg = eb[2*H_+j], go = eb[3*H_+j];
            #pragma unroll
            for (int ks=0; ks<8; ks++){
                const float* g = gp + ((size_t)(ks*B_ + b))*G4H;
                gi += g[j]; gf += g[H_+j]; gg += g[2*H_+j]; go += g[3*H_+j];
            }
            float ig = sigmoidf_(gi), fg = sigmoidf_(gf);
            float g2 = fast_tanh(gg), og = sigmoidf_(go);
            float c = fg*cbuf2[((t-1)&1)*65536 + b*H_+j] + ig*g2;
            float h = og*fast_tanh(c);
            ushort_t hb = f2b(h);
            if (half == 0){           // cross-step writes ordered by the gates_k launch boundary
                cbuf2[(t&1)*65536 + b*H_+j] = c;
                xcat[(size_t)b*KCAT + D_ + j] = hb;
                Hall[((size_t)(t-1)*B_ + b)*H_ + j] = hb;
            }
            hls[j] = hb;
            dv = h * beta_W[j];
        }
        #pragma unroll
        for (int off=32; off; off>>=1) dv += __shfl_down(dv, off);
        if (lane==0) red[wave] = dv;
        __syncthreads();
        if (tid == 0){
            float s = 0.f;
            #pragma unroll
            for (int w=0; w<8; w++) s += red[w];
            bdot_s = s;
        }
        // full hW = h @ Whc (K=512); 16 waves x 32 cols -> hWl
        int wn = wave * 32;
        int col16 = lane & 15;
        int khi = (lane >> 4) * 8;
        bool a_on = (col16 == 0);
        f32x4 acc[2];
        acc[0] = (f32x4){0.f,0.f,0.f,0.f};
        acc[1] = (f32x4){0.f,0.f,0.f,0.f};
        #pragma unroll
        for (int kk=0; kk<16; kk++){
            bf16x8 af = (bf16x8){0,0,0,0,0,0,0,0};
            if (a_on) af = *(const bf16x8*)&hls[kk*32 + khi];
            #pragma unroll
            for (int f=0;f<2;f++){
                bf16x8 bf = *(const bf16x8*)(WhcT + (size_t)(wn + f*16 + col16)*512 + kk*32 + khi);
                acc[f] = __builtin_amdgcn_mfma_f32_16x16x32_bf16(af, bf, acc[f], 0, 0, 0);
            }
        }
        if (lane < 16){
            #pragma unroll
            for (int f=0;f<2;f++) hWl[wn + f*16 + lane] = acc[f][0];
        }
    } else {
        if (tid < 512) hWl[tid] = hW0[(size_t)b*512 + tid];
        if (tid == 0) bdot_s = bdot0[b];
    }
    __syncthreads();
    // ---- phase E: e over own l-half (16 waves), own results also to LDS ----
    {
        float4 hw0v = *(float4*)&hWl[lane*8];
        float4 hw1v = *(float4*)&hWl[lane*8 + 4];
        const float* vp = v + lane*8;
        float4 v0 = *(const float4*)vp, v1 = *(const float4*)(vp+4);
        const int l0 = half*LH;
        for (int r = wave; r < LH; r += 16){
            int4 raw = *(const int4*)(wa + (((size_t)(b*L_ + l0 + r))<<9) + lane*8);
            const unsigned* u = (const unsigned*)&raw;
            float s;
            s  = fast_tanh(b2f_lo(u[0]) + hw0v.x)*v0.x;
            s += fast_tanh(b2f_hi(u[0]) + hw0v.y)*v0.y;
            s += fast_tanh(b2f_lo(u[1]) + hw0v.z)*v0.z;
            s += fast_tanh(b2f_hi(u[1]) + hw0v.w)*v0.w;
            s += fast_tanh(b2f_lo(u[2]) + hw1v.x)*v1.x;
            s += fast_tanh(b2f_hi(u[2]) + hw1v.y)*v1.y;
            s += fast_tanh(b2f_lo(u[3]) + hw1v.z)*v1.z;
            s += fast_tanh(b2f_hi(u[3]) + hw1v.w)*v1.w;
            #pragma unroll
            for (int off=32; off; off>>=1) s += __shfl_down(s, off);
            if (lane==0){ ebuf[b*L_ + l0 + r] = s; e_s[r] = s; }
        }
    }
    // ---- pair sync (the only one): e complete on both halves ----
    __syncthreads();
    if (tid == 0){
        __threadfence();
        atomicAdd(&ebar[b], 1u);
        const unsigned tgt = 2u*(unsigned)(t+1);
        while (__hip_atomic_load(&ebar[b], __ATOMIC_ACQUIRE, __HIP_MEMORY_SCOPE_AGENT) < tgt)
            __builtin_amdgcn_s_sleep(1);
    }
    __syncthreads();
    // ---- softmax over all 196: own half from LDS, sibling from global ----
    const int l0 = half*LH;
    float ev = -3.0e38f;
    if (tid < L_){
        int loc = tid - l0;
        ev = (loc >= 0 && loc < LH) ? e_s[loc] : ebuf[b*L_ + tid];
    }
    float wmax = ev;
    #pragma unroll
    for (int off=32; off; off>>=1) wmax = fmaxf(wmax, __shfl_down(wmax, off));
    if (lane==0) red[wave] = wmax;
    __syncthreads();
    float m = red[0];
    #pragma unroll
    for (int w=1; w<16; w++) m = fmaxf(m, red[w]);
    float pr = (tid < L_) ? __expf(ev - m) : 0.f;
    float wsum = pr;
    #pragma unroll
    for (int off=32; off; off>>=1) wsum += __shfl_down(wsum, off);
    if (lane==0) red[16+wave] = wsum;
    __syncthreads();
    float sum = red[16];
    #pragma unroll
    for (int w=1; w<16; w++) sum += red[16+w];
    float inv = 1.f / sum;
    if (tid < L_) al_s[tid] = pr*inv;
    if (tid >= l0 && tid < l0 + LH)
        __builtin_nontemporal_store(pr*inv, alphas_out + (size_t)b*TM1*L_ + (size_t)t*L_ + tid);
    __syncthreads();
    // ---- ctx: 256 d's per block, 4 d's per thread (uint2), 16-way l split ----
    {
        const int dg = tid & 63;
        const int lr = tid >> 6;            // 0..15
        const int d0 = half*256 + dg*4;
        const ushort_t* pa = a_b + (((size_t)(b*L_))<<9) + d0;
        float4 s = make_float4(0.f,0.f,0.f,0.f);
        for (int l = lr; l < L_; l += 16){
            uint2 av = *(const uint2*)(pa + ((size_t)l<<9));
            float al = al_s[l];
            s.x = fmaf(al, b2f_lo(av.x), s.x);
            s.y = fmaf(al, b2f_hi(av.x), s.y);
            s.z = fmaf(al, b2f_lo(av.y), s.z);
            s.w = fmaf(al, b2f_hi(av.y), s.w);
        }
        part4[lr][dg] = s;
        __syncthreads();
        if (tid < 64){
            float beta = sigmoidf_(bdot_s + beta_b[0]);
            float4 r = make_float4(0.f,0.f,0.f,0.f);
            #pragma unroll
            for (int q=0;q<16;q++){
                float4 pv = part4[q][tid];
                r.x += pv.x; r.y += pv.y; r.z += pv.z; r.w += pv.w;
            }
            unsigned lo = (unsigned)f2b(beta*r.x) | (((unsigned)f2b(beta*r.y))<<16);
            unsigned hi = (unsigned)f2b(beta*r.z) | (((unsigned)f2b(beta*r.w))<<16);
            uint2 pk; pk.x = lo; pk.y = hi;
            *(uint2*)(xcat + (size_t)b*KCAT + half*256 + tid*4) = pk;
        }
    }
}

// gates partials: grid (32, 8) x 256; tile M128 x N64, K-chunk 128
__global__ __launch_bounds__(256) void gates_k(const ushort_t* __restrict__ xcat,
                        const ushort_t* __restrict__ WcatT, float* __restrict__ gp){
    __shared__ ushort_t As[128*32];
    __shared__ ushort_t Bs[64*32];
    const int bn = blockIdx.x*64;
    const int ks = blockIdx.y;
    const int tid = threadIdx.x;
    const int lane = tid & 63, wave = tid >> 6;
    const int wm = wave*32;
    const int lrow = lane & 15;
    const int lk8 = (lane >> 4) * 8;
    f32x4 acc[2][4];
    #pragma unroll
    for (int i=0;i<2;i++)
        #pragma unroll
        for (int j=0;j<4;j++) acc[i][j] = (f32x4){0.f,0.f,0.f,0.f};

    for (int kk = 0; kk < 4; ++kk){
        int k0 = ks*128 + kk*32;
        int c0 = 2*tid;
        int r0 = c0 >> 2,  kq0 = (c0 & 3)*8;
        int r1 = (c0+1) >> 2, kq1 = ((c0+1) & 3)*8;
        int4 a0 = *(const int4*)(xcat + (size_t)r0*KCAT + k0 + kq0);
        int4 a1 = *(const int4*)(xcat + (size_t)r1*KCAT + k0 + kq1);
        int rb = tid >> 2, kqb = (tid & 3)*8;
        int4 b0 = *(const int4*)(WcatT + (size_t)(bn+rb)*KCAT + k0 + kqb);
        __syncthreads();
        *(int4*)&As[r0*32 + kq0] = a0;
        *(int4*)&As[r1*32 + kq1] = a1;
        *(int4*)&Bs[rb*32 + kqb] = b0;
        __syncthreads();
        bf16x8 af[2], bfr[4];
        #pragma unroll
        for (int i=0;i<2;i++) af[i] = *(bf16x8*)&As[(wm + i*16 + lrow)*32 + lk8];
        #pragma unroll
        for (int j=0;j<4;j++) bfr[j] = *(bf16x8*)&Bs[(j*16 + lrow)*32 + lk8];
        #pragma unroll
        for (int i=0;i<2;i++)
            #pragma unroll
            for (int j=0;j<4;j++)
                acc[i][j] = __builtin_amdgcn_mfma_f32_16x16x32_bf16(af[i], bfr[j], acc[i][j], 0, 0, 0);
    }
    const int rq = (lane >> 4) * 4;
    #pragma unroll
    for (int i=0;i<2;i++){
        #pragma unroll
        for (int j=0;j<4;j++){
            int gcol = bn + j*16 + lrow;
            #pragma unroll
            for (int q=0;q<4;q++){
                int grow = wm + i*16 + rq + q;
                gp[((size_t)(ks*B_ + grow))*G4H + gcol] = acc[i][j][q];
            }
        }
    }
}

// final lstm (h_19 -> Hall[18]); grid B x 512; reads cbuf2 parity 0 (after t=18)
__global__ __launch_bounds__(512) void lstmfin_k(const float* __restrict__ gp, const float* __restrict__ embWih,
                       const float* __restrict__ cbuf2, ushort_t* __restrict__ Hall){
    int b = blockIdx.x, j = threadIdx.x;
    const float* eb = embWih + ((size_t)(18*B_ + b))*G4H;
    float gi = eb[j], gf = eb[H_+j], gg = eb[2*H_+j], go = eb[3*H_+j];
    #pragma unroll
    for (int ks=0; ks<8; ks++){
        const float* g = gp + ((size_t)(ks*B_ + b))*G4H;
        gi += g[j]; gf += g[H_+j]; gg += g[2*H_+j]; go += g[3*H_+j];
    }
    float ig = sigmoidf_(gi), fg = sigmoidf_(gf);
    float g2 = fast_tanh(gg), og = sigmoidf_(go);
    float c = fg*cbuf2[b*H_+j] + ig*g2;
    float h = og*fast_tanh(c);
    Hall[((size_t)18*B_ + b)*H_ + j] = f2b(h);
}

extern "C" void kernel_launch(void* const* d_in, const int* in_sizes, int n_in,
                              void* d_out, int out_size, void* d_ws, size_t ws_size,
                              hipStream_t stream) {
    const float* a      = (const float*)d_in[0];
    const int*   caps   = (const int*)  d_in[1];
    const float* embW   = (const float*)d_in[3];
    const float* Wa     = (const float*)d_in[4];
    const float* Wh     = (const float*)d_in[5];
    const float* Wc     = (const float*)d_in[6];
    const float* v      = (const float*)d_in[7];
    const float* beta_W = (const float*)d_in[8];
    const float* beta_b = (const float*)d_in[9];
    const float* W_ih   = (const float*)d_in[10];
    const float* W_hh   = (const float*)d_in[11];
    const float* b_ih   = (const float*)d_in[12];
    const float* b_hh   = (const float*)d_in[13];
    const float* fc_W   = (const float*)d_in[14];
    const float* fc_b   = (const float*)d_in[15];
    const float* iWh    = (const float*)d_in[16];
    const float* ibh    = (const float*)d_in[17];
    const float* iWc    = (const float*)d_in[18];
    const float* ibc    = (const float*)d_in[19];

    float* out    = (float*)d_out;
    float* alphas = out + (size_t)ROWS*V_;

    // d_out scratch (dead before final logits GEMM overwrites it)
    char* ob = (char*)d_out;
    ushort_t* wa_b   = (ushort_t*)(ob);               // 25,690,112 B
    ushort_t* a_b    = (ushort_t*)(ob + 25690112);    // 25,690,112 B
    float*    embWih = (float*)   (ob + 51380224);    // 19,922,944 B

    // d_ws layout (byte offsets)
    char* wb = (char*)d_ws;
    float* mcp      = (float*)(wb);              // 1,048,576
    float* bdot0    = (float*)(wb + 1048576);    // 4096
    float* cbuf2    = (float*)(wb + 1052672);    // 524288 (2 parities)
    float* h0f      = (float*)(wb + 1576960);    // 262144
    float* hW0      = (float*)(wb + 1839104);    // 262144
    float* ebuf     = (float*)(wb + 2101248);    // 102400
    float* bias4h   = (float*)(wb + 2203648);    // 8192
    unsigned* bars  = (unsigned*)(wb + 2211840); // 4096: ebar[0..127]
    float* gp       = (float*)(wb + 2215936);    // 8388608
    ushort_t* xcat_b = (ushort_t*)(wb + 10604544);  // 262144
    ushort_t* xemb_b = (ushort_t*)(wb + 10866688);  // 1245184
    ushort_t* Hall   = (ushort_t*)(wb + 12111872);  // 2490368
    ushort_t* WaT    = (ushort_t*)(wb + 14602240);  // 524288
    ushort_t* WhcT   = (ushort_t*)(wb + 15126528);  // 524288
    ushort_t* WihT   = (ushort_t*)(wb + 15650816);  // 1048576
    ushort_t* WcatT  = (ushort_t*)(wb + 16699392);  // 4194304
    ushort_t* fcWT   = (ushort_t*)(wb + 20893696);  // 10354688 -> ends ~29.8MB

    // ---- prep (1 launch; mean blocks first so they overlap the transposes) ----
    PrepArgs P;
    P.j[0] = { Wa,   nullptr, WaT,  512, 512, 512,  0,   512,  16, 256 };
    P.j[1] = { Wh,   Wc,      WhcT, 512, 512, 512,  0,   512,  16, 256 };
    P.j[2] = { W_ih, nullptr, WihT, G4H, 256, G4H,  0,   256,  64, 512 };
    P.j[3] = { W_ih + (size_t)E_*G4H, nullptr, WcatT, G4H, 512, G4H, 0,   KCAT, 64, 1024 };
    P.j[4] = { W_hh, nullptr, WcatT, G4H, 512, G4H,  512, KCAT, 64, 1024 };
    P.j[5] = { fc_W, nullptr, fcWT, V_,  512, V_,   0,   512,  316, 5056 };
    P.a = a; P.a_b = a_b; P.mcp = mcp;
    P.b_ih = b_ih; P.b_hh = b_hh; P.bias4h = bias4h; P.bars = bars;
    P.caps = caps; P.embW = embW; P.xemb = xemb_b;
    prep_all_k<<<8993, 256, 0, stream>>>(P);

    gemm64t2<<<dim3(8,2,2), 256, 0, stream>>>(mcp, D_, iWh, iWc, H_, h0f, cbuf2, H_, ibh, ibc);
    hw0cvt_k<<<B_, 512, 0, stream>>>(h0f, WhcT, beta_W, xcat_b, hW0, bdot0);

    // wa_b + embWih in one dispatch
    GJob g0 = { a_b,    512, WaT,  512, wa_b,   512, 512,  512, nullptr, 1, 4,  784 };
    GJob g1 = { xemb_b, 256, WihT, 256, embWih, G4H, G4H,  256, bias4h,  0, 16, 304 };
    gemm_dual_k<<<1088, 256, 0, stream>>>(g0, g1);

    // ---- loop: 2 kernels/step, single pair-sync inside mega2 ----
    for (int t = 0; t < TM1; ++t){
        mega2_k<<<dim3(B_,2), 1024, 0, stream>>>(wa_b, a_b, v, beta_W, beta_b, WhcT,
                                                 gp, embWih, cbuf2, hW0, bdot0, xcat_b, Hall,
                                                 alphas, ebuf, bars, t);
        gates_k<<<dim3(32,8), 256, 0, stream>>>(xcat_b, WcatT, gp);
    }
    lstmfin_k<<<B_, 512, 0, stream>>>(gp, embWih, cbuf2, Hall);

    // logits = Hall @ fc_W + fc_b   (2432 x 10000 x 512)
    gemm_logits_k<<<dim3(1520), 256, 0, stream>>>(Hall, H_, fcWT, H_, out, V_, V_, H_, fc_b);
}

// Round 17
// 963.809 us; speedup vs baseline: 1.4936x; 1.0032x over previous
//
#include <hip/hip_runtime.h>
#include <hip/hip_bf16.h>
#include <math.h>

#define B_ 128
#define L_ 196
#define D_ 512
#define T_ 20
#define V_ 10000
#define E_ 256
#define H_ 512
#define A_ 512
#define TM1 19
#define ROWS (TM1*B_)      /* 2432 */
#define G4H 2048
#define KCAT 1024
#define LH 98

typedef unsigned short ushort_t;
typedef __attribute__((ext_vector_type(8))) short bf16x8;
typedef __attribute__((ext_vector_type(4))) float f32x4;

__device__ __forceinline__ float fast_tanh(float x){
    float ax = fabsf(x);
    float e = __expf(-2.f*ax);
    float r = __builtin_amdgcn_rcpf(1.f + e);
    return copysignf((1.f - e)*r, x);
}
__device__ __forceinline__ float sigmoidf_(float x){
    return __builtin_amdgcn_rcpf(1.f + __expf(-x));
}
__device__ __forceinline__ ushort_t f2b(float f){
    union{float f; unsigned u;} x; x.f = f;
    unsigned r = x.u + 0x7fffu + ((x.u>>16)&1u);
    return (ushort_t)(r>>16);
}
__device__ __forceinline__ float b2f(ushort_t h){
    union{unsigned u; float f;} x; x.u = ((unsigned)h)<<16;
    return x.f;
}
__device__ __forceinline__ float b2f_lo(unsigned u){ union{unsigned u; float f;} x; x.u = u<<16; return x.f; }
__device__ __forceinline__ float b2f_hi(unsigned u){ union{unsigned u; float f;} x; x.u = u & 0xffff0000u; return x.f; }

#define GL16(gsrc, ldst) __builtin_amdgcn_global_load_lds( \
    (const __attribute__((address_space(1))) unsigned*)(gsrc), \
    (__attribute__((address_space(3))) unsigned*)(ldst), 16, 0, 0)

// ========== logits GEMM: BK=64, swizzled staging, XCD swizzle, LDS-coalesced NT epilogue ==========
// LDS layout per buffer: [128 rows][64 k] bf16; phys slot q of row r holds logical k = q ^ ((r&7)<<3)
__global__ __launch_bounds__(256)
void gemm_logits_k(const ushort_t* __restrict__ A, int lda,
                   const ushort_t* __restrict__ BT, int ldb,
                   float* __restrict__ C, int ldc,
                   int N, int K, const float* __restrict__ bias)
{
    __shared__ ushort_t As[2][8192];
    __shared__ ushort_t Bs[2][8192];
    int bid = blockIdx.x;
    int swz = (bid & 7)*190 + (bid >> 3);
    int mt = swz % 19, nt = swz / 19;
    if (nt >= 79) return;
    const int bm = mt*128, bn = nt*128;
    const int tid = threadIdx.x;
    const int lane = tid & 63;
    const int wave = tid >> 6;
    const int wm = (wave >> 1) * 64;
    const int wn = (wave & 1) * 64;
    const int lrow = lane & 15;
    const int lk8  = (lane >> 4) * 8;
    const int srow8 = lane >> 3;                 // 0..7 within 8-row slab
    const int sk8s  = ((lane & 7) * 8) ^ (srow8 << 3);   // swizzled source k-offset

    f32x4 acc[4][4];
    #pragma unroll
    for (int i=0;i<4;i++)
        #pragma unroll
        for (int j=0;j<4;j++) acc[i][j] = (f32x4){0.f,0.f,0.f,0.f};

    // stage one K=64 tile into buffer nb: 4 slabs of 8 rows per wave for A and B
    #define STAGE_LOGITS(nb, k0s) { \
        _Pragma("unroll") \
        for (int i=0;i<4;i++){ \
            int s = wave + i*4; \
            GL16(A  + (size_t)(bm + s*8 + srow8)*lda + (k0s) + sk8s, &As[nb][s*512]); \
            GL16(BT + (size_t)(bn + s*8 + srow8)*ldb + (k0s) + sk8s, &Bs[nb][s*512]); \
        } }

    STAGE_LOGITS(0, 0)

    int buf = 0;
    for (int k0 = 0; k0 < K; k0 += 64) {
        asm volatile("s_waitcnt vmcnt(0)" ::: "memory");
        __syncthreads();
        if (k0 + 64 < K){
            int nb = buf ^ 1;
            STAGE_LOGITS(nb, k0 + 64)
        }
        #pragma unroll
        for (int kk = 0; kk < 2; ++kk){
            bf16x8 af[4], bfr[4];
            #pragma unroll
            for (int i=0;i<4;i++){
                int r = wm + i*16 + lrow;
                af[i]  = *(bf16x8*)&As[buf][r*64 + ((kk*32 + lk8) ^ ((r & 7) << 3))];
            }
            #pragma unroll
            for (int j=0;j<4;j++){
                int r = wn + j*16 + lrow;
                bfr[j] = *(bf16x8*)&Bs[buf][r*64 + ((kk*32 + lk8) ^ ((r & 7) << 3))];
            }
            #pragma unroll
            for (int i=0;i<4;i++)
                #pragma unroll
                for (int j=0;j<4;j++)
                    acc[i][j] = __builtin_amdgcn_mfma_f32_16x16x32_bf16(af[i], bfr[j], acc[i][j], 0, 0, 0);
        }
        buf ^= 1;
    }
    #undef STAGE_LOGITS

    // epilogue: stage 32x128 f32 chunks in LDS, coalesced NT float4 stores
    const int rq = (lane >> 4) * 4;
    float* eps = (float*)As;
    #pragma unroll
    for (int c = 0; c < 4; ++c){
        __syncthreads();
        if ((wave >> 1) == (c >> 1)){
            const int ib = 2*(c & 1);
            #pragma unroll
            for (int ii = 0; ii < 2; ++ii){
                #pragma unroll
                for (int j = 0; j < 4; ++j){
                    #pragma unroll
                    for (int q = 0; q < 4; ++q){
                        int lr_ = ii*16 + rq + q;
                        int lc  = wn + j*16 + lrow;
                        eps[lr_*128 + lc] = acc[ib+ii][j][q];
                    }
                }
            }
        }
        __syncthreads();
        for (int it = tid; it < 1024; it += 256){
            int r = it >> 5, c4 = it & 31;
            int col0 = bn + c4*4;
            if (col0 >= N) continue;
            f32x4 vv = *(f32x4*)&eps[r*128 + c4*4];
            float* dst = &C[(size_t)(bm + 32*c + r)*ldc + col0];
            if (col0 + 3 < N){
                float4 bb = *(const float4*)(bias + col0);
                vv[0] += bb.x; vv[1] += bb.y; vv[2] += bb.z; vv[3] += bb.w;
                __builtin_nontemporal_store(vv, (f32x4*)dst);
            } else {
                for (int e=0; e<4 && col0+e < N; ++e)
                    __builtin_nontemporal_store(vv[e] + bias[col0+e], dst + e);
            }
        }
    }
}

// ================= dual GEMM (wa + embWih in one dispatch), runtime job =================
struct GJob { const ushort_t* A; int lda; const ushort_t* BT; int ldb;
              void* C; int ldc; int N, K; const float* bias; int out_bf16; int nx; int nblk; };

__global__ __launch_bounds__(256) void gemm_dual_k(GJob j0, GJob j1){
    __shared__ ushort_t As[2][4096];
    __shared__ ushort_t Bs[2][4096];
    int bid = blockIdx.x;
    GJob jb = (bid < j0.nblk) ? j0 : j1;
    if (bid >= j0.nblk) bid -= j0.nblk;
    const int bn = (bid % jb.nx)*128, bm = (bid / jb.nx)*128;
    const int tid = threadIdx.x;
    const int lane = tid & 63;
    const int wave = tid >> 6;
    const int wm = (wave >> 1) * 64;
    const int wn = (wave & 1) * 64;
    const int lrow = lane & 15;
    const int lk8  = (lane >> 4) * 8;
    const int srow = tid >> 2;
    const int skq0 = (tid & 3) * 8;
    const int wbase = wave * 512;

    f32x4 acc[4][4];
    #pragma unroll
    for (int i=0;i<4;i++)
        #pragma unroll
        for (int j=0;j<4;j++) acc[i][j] = (f32x4){0.f,0.f,0.f,0.f};

    const ushort_t* Ab = jb.A  + (size_t)(bm+srow)*jb.lda + skq0;
    const ushort_t* Bb = jb.BT + (size_t)(bn+srow)*jb.ldb + skq0;

    GL16(Ab,                        &As[0][wbase]);
    GL16(Ab + (size_t)64*jb.lda,    &As[0][2048 + wbase]);
    GL16(Bb,                        &Bs[0][wbase]);
    GL16(Bb + (size_t)64*jb.ldb,    &Bs[0][2048 + wbase]);

    int buf = 0;
    for (int k0 = 0; k0 < jb.K; k0 += 32) {
        asm volatile("s_waitcnt vmcnt(0)" ::: "memory");
        __syncthreads();
        if (k0 + 32 < jb.K){
            int nb = buf ^ 1;
            GL16(Ab + k0 + 32,                      &As[nb][wbase]);
            GL16(Ab + (size_t)64*jb.lda + k0 + 32,  &As[nb][2048 + wbase]);
            GL16(Bb + k0 + 32,                      &Bs[nb][wbase]);
            GL16(Bb + (size_t)64*jb.ldb + k0 + 32,  &Bs[nb][2048 + wbase]);
        }
        bf16x8 af[4], bfr[4];
        #pragma unroll
        for (int i=0;i<4;i++) af[i]  = *(bf16x8*)&As[buf][(wm + i*16 + lrow)*32 + lk8];
        #pragma unroll
        for (int j=0;j<4;j++) bfr[j] = *(bf16x8*)&Bs[buf][(wn + j*16 + lrow)*32 + lk8];
        #pragma unroll
        for (int i=0;i<4;i++)
            #pragma unroll
            for (int j=0;j<4;j++)
                acc[i][j] = __builtin_amdgcn_mfma_f32_16x16x32_bf16(af[i], bfr[j], acc[i][j], 0, 0, 0);
        buf ^= 1;
    }

    const int rq = (lane >> 4) * 4;
    #pragma unroll
    for (int j=0;j<4;j++){
        int col = bn + wn + j*16 + lrow;
        if (col >= jb.N) continue;
        float bv = jb.bias ? jb.bias[col] : 0.f;
        #pragma unroll
        for (int i=0;i<4;i++){
            #pragma unroll
            for (int q=0;q<4;q++){
                int row = bm + wm + i*16 + rq + q;
                float v = acc[i][j][q] + bv;
                if (jb.out_bf16) ((ushort_t*)jb.C)[(size_t)row*jb.ldc + col] = f2b(v);
                else             ((float*)jb.C)[(size_t)row*jb.ldc + col] = v;
            }
        }
    }
}

// ===== f32 tile GEMM (init path): C = tanh((Σ mcp partials)/L @ B + bias), z picks job =====
__global__ __launch_bounds__(256) void gemm64t2(const float* __restrict__ Amcp, int lda,
                       const float* __restrict__ B0, const float* __restrict__ B1, int ldb,
                       float* __restrict__ C0, float* __restrict__ C1, int ldc,
                       const float* __restrict__ bias0, const float* __restrict__ bias1)
{
    const float* Bm  = blockIdx.z ? B1 : B0;
    float* C         = blockIdx.z ? C1 : C0;
    const float* bias= blockIdx.z ? bias1 : bias0;
    __shared__ float As[16][65];
    __shared__ float Bs[16][65];
    int bm = blockIdx.y*64, bn = blockIdx.x*64;
    int tid = threadIdx.x;
    int tx = tid & 15, ty = tid >> 4;
    const float invL = 1.f/(float)L_;
    float acc[4][4] = {};
    for (int k0 = 0; k0 < D_; k0 += 16) {
        {
            int r  = tid >> 2;
            int kq = (tid & 3) * 4;
            const float* Ap = Amcp + (size_t)(bm+r)*lda + k0 + kq;
            float4 v0 = *(const float4*)(Ap);
            float4 v1 = *(const float4*)(Ap + 65536);
            float4 v2 = *(const float4*)(Ap + 131072);
            float4 v3 = *(const float4*)(Ap + 196608);
            float4 va = make_float4((v0.x+v1.x+v2.x+v3.x)*invL, (v0.y+v1.y+v2.y+v3.y)*invL,
                                    (v0.z+v1.z+v2.z+v3.z)*invL, (v0.w+v1.w+v2.w+v3.w)*invL);
            As[kq+0][r]=va.x; As[kq+1][r]=va.y; As[kq+2][r]=va.z; As[kq+3][r]=va.w;
        }
        {
            int kk = tid >> 4;
            int nq = (tid & 15) * 4;
            float4 vb = *(const float4*)(Bm + (size_t)(k0+kk)*ldb + bn + nq);
            Bs[kk][nq+0]=vb.x; Bs[kk][nq+1]=vb.y; Bs[kk][nq+2]=vb.z; Bs[kk][nq+3]=vb.w;
        }
        __syncthreads();
        #pragma unroll
        for (int k = 0; k < 16; ++k) {
            float a0[4], b0[4];
            #pragma unroll
            for (int i=0;i<4;i++) a0[i] = As[k][ty*4+i];
            #pragma unroll
            for (int j=0;j<4;j++) b0[j] = Bs[k][tx*4+j];
            #pragma unroll
            for (int i=0;i<4;i++)
                #pragma unroll
                for (int j=0;j<4;j++)
                    acc[i][j] = fmaf(a0[i], b0[j], acc[i][j]);
        }
        __syncthreads();
    }
    #pragma unroll
    for (int i=0;i<4;i++){
        int row = bm + ty*4 + i;
        #pragma unroll
        for (int j=0;j<4;j++){
            int col = bn + tx*4 + j;
            C[(size_t)row*ldc + col] = fast_tanh(acc[i][j] + bias[col]);
        }
    }
}

// ================= fused prep: mean/cvt FIRST + 6 transposes + bias/bars + emb gather =================
struct TJob { const float* src; const float* src2; ushort_t* dst;
              int lds, Ksz, Nsz, koff, ldk, nx, nblk; };
struct PrepArgs {
    TJob j[6];
    const float* a; ushort_t* a_b; float* mcp;
    const float* b_ih; const float* b_hh; float* bias4h; unsigned* bars;
    const int* caps; const float* embW; ushort_t* xemb;
};

__global__ __launch_bounds__(256) void prep_all_k(PrepArgs P){
    __shared__ float t[32][33];
    int bid = blockIdx.x;
    const int tid = threadIdx.x;
    if (bid < 256){
        const int b = bid >> 1, half = bid & 1;
        const int quad = tid & 127;
        const int sl = tid >> 7;
        const int pi = half*2 + sl;
        const int l0 = half*LH + sl*49;
        const float* p = P.a + ((size_t)(b*L_ + l0))*D_ + quad*4;
        ushort_t* q = P.a_b + ((size_t)(b*L_ + l0))*D_ + quad*4;
        float4 s = make_float4(0.f,0.f,0.f,0.f);
        for (int l=0;l<49;l++){
            float4 v = *(const float4*)(p + (size_t)l*D_);
            s.x += v.x; s.y += v.y; s.z += v.z; s.w += v.w;
            ushort_t r[4] = {f2b(v.x),f2b(v.y),f2b(v.z),f2b(v.w)};
            *(uint2*)(q + (size_t)l*D_) = *(uint2*)r;
        }
        *(float4*)(P.mcp + (size_t)pi*65536 + (size_t)b*D_ + quad*4) = s;
        return;
    }
    bid -= 256;
    if (bid < 8128){
        int ji = 0;
        while (bid >= P.j[ji].nblk){ bid -= P.j[ji].nblk; ji++; }
        const TJob jb = P.j[ji];
        int n0 = (bid % jb.nx)*32, k0 = (bid / jb.nx)*32;
        int tx = tid & 31, ty = tid >> 5;
        #pragma unroll
        for (int kk = ty; kk < 32; kk += 8){
            int k = k0 + kk, n = n0 + tx;
            float v = 0.f;
            if (k < jb.Ksz && n < jb.Nsz){
                v = jb.src[(size_t)k*jb.lds + n];
                if (jb.src2) v += jb.src2[(size_t)k*jb.lds + n];
            }
            t[kk][tx] = v;
        }
        __syncthreads();
        #pragma unroll
        for (int nn = ty; nn < 32; nn += 8){
            int n = n0 + nn, k = k0 + tx;
            if (k < jb.Ksz) jb.dst[(size_t)n*jb.ldk + jb.koff + k] = f2b(t[tx][nn]);
        }
        return;
    }
    bid -= 8128;
    if (bid == 0){
        for (int k = tid; k < G4H; k += 256) P.bias4h[k] = P.b_ih[k] + P.b_hh[k];
        P.bars[tid] = 0u;
        return;
    }
    bid -= 1;
    int i = bid*4 + (tid >> 6);
    int lane = tid & 63;
    int tt = i / B_, b = i - tt*B_;
    int cap = P.caps[b*T_ + tt];
    float4 v = ((const float4*)(P.embW + (size_t)cap*E_))[lane];
    ushort_t r[4] = {f2b(v.x),f2b(v.y),f2b(v.z),f2b(v.w)};
    *(uint2*)(P.xemb + (size_t)i*E_ + lane*4) = *(uint2*)r;
}

// h0: cvt to xcat + full hW0 + beta-dot; grid B x 512
__global__ __launch_bounds__(512) void hw0cvt_k(const float* __restrict__ h0f,
                        const ushort_t* __restrict__ WhcT, const float* __restrict__ beta_W,
                        ushort_t* __restrict__ xcat, float* __restrict__ hW0, float* __restrict__ bdot0){
    int b = blockIdx.x, tid = threadIdx.x;
    int lane = tid & 63, wave = tid >> 6;
    __shared__ ushort_t hls[512];
    __shared__ float rr[8];
    float hv = h0f[b*H_ + tid];
    ushort_t hb = f2b(hv);
    xcat[(size_t)b*KCAT + D_ + tid] = hb;
    hls[tid] = hb;
    float dv = hv * beta_W[tid];
    #pragma unroll
    for (int off=32; off; off>>=1) dv += __shfl_down(dv, off);
    if (lane==0) rr[wave] = dv;
    __syncthreads();
    if (tid == 0)
        bdot0[b] = rr[0]+rr[1]+rr[2]+rr[3]+rr[4]+rr[5]+rr[6]+rr[7];
    int wn = wave * 64;
    int col16 = lane & 15;
    int khi = (lane >> 4) * 8;
    bool a_on = (col16 == 0);
    f32x4 acc[4];
    #pragma unroll
    for (int f=0;f<4;f++) acc[f] = (f32x4){0.f,0.f,0.f,0.f};
    for (int kk=0; kk<16; kk++){
        bf16x8 af = (bf16x8){0,0,0,0,0,0,0,0};
        if (a_on) af = *(const bf16x8*)&hls[kk*32 + khi];
        #pragma unroll
        for (int f=0;f<4;f++){
            bf16x8 bf = *(const bf16x8*)(WhcT + (size_t)(wn + f*16 + col16)*512 + kk*32 + khi);
            acc[f] = __builtin_amdgcn_mfma_f32_16x16x32_bf16(af, bf, acc[f], 0, 0, 0);
        }
    }
    if (lane < 16){
        #pragma unroll
        for (int f=0;f<4;f++) hW0[(size_t)b*512 + wn + f*16 + lane] = acc[f][0];
    }
}

// ====== mega2 (1024 thr): full-duplicated lstm(t-1) + local hW -> e -> 1 pair-sync -> softmax/ctx ======
// grid (B_, 2) x 1024; ONE pair-sync per step (e-exchange) via monotonic ebar[b]
__global__ __launch_bounds__(1024) void mega2_k(const ushort_t* __restrict__ wa,
                        const ushort_t* __restrict__ a_b,
                        const float* __restrict__ v,
                        const float* __restrict__ beta_W, const float* __restrict__ beta_b,
                        const ushort_t* __restrict__ WhcT,
                        const float* __restrict__ gp, const float* __restrict__ embWih,
                        float* __restrict__ cbuf2, const float* __restrict__ hW0,
                        const float* __restrict__ bdot0,
                        ushort_t* __restrict__ xcat, ushort_t* __restrict__ Hall,
                        float* __restrict__ alphas_out, float* __restrict__ ebuf,
                        unsigned* __restrict__ ebar, int t)
{
    const int b = blockIdx.x, half = blockIdx.y;
    const int tid = threadIdx.x;                  // 0..1023, 16 waves
    const int lane = tid & 63, wave = tid >> 6;
    __shared__ ushort_t hls[512];
    __shared__ float hWl[512];
    __shared__ float red[32];
    __shared__ float al_s[224];
    __shared__ float e_s[LH];
    __shared__ float bdot_s;
    __shared__ float4 part4[16][64];

    // ---- phase L: FULL lstm (duplicated across pair) + beta dot + FULL hW into LDS ----
    if (t > 0){
        float dv = 0.f;
        if (tid < 512){
            const int j = tid;
            const float* eb = embWih + ((size_t)((t-1)*B_ + b))*G4H;
            float gi = eb[j], gf = eb[H_+j], gg = eb[2*H_+j], go = eb[3*H_+j];
            #pragma unroll
            for (int ks=0; ks<8; ks++){
                const float* g = gp + ((size_t)(ks*B_ + b))*G4H;
                gi += g[j]; gf += g[H_+j]; gg += g[2*H_+j]; go += g[3*H_+j];
            }
            float ig = sigmoidf_(gi), fg = sigmoidf_(gf);
            float g2 = fast_tanh(gg), og = sigmoidf_(go);
            float c = fg*cbuf2[((t-1)&1)*65536 + b*H_+j] + ig*g2;
            float h = og*fast_tanh(c);
            ushort_t hb = f2b(h);
            if (half == 0){           // cross-step writes ordered by the gates_k launch boundary
                cbuf2[(t&1)*65536 + b*H_+j] = c;
                xcat[(size_t)b*KCAT + D_ + j] = hb;
                Hall[((size_t)(t-1)*B_ + b)*H_ + j] = hb;
            }
            hls[j] = hb;
            dv = h * beta_W[j];
        }
        #pragma unroll
        for (int off=32; off; off>>=1) dv += __shfl_down(dv, off);
        if (lane==0) red[wave] = dv;
        __syncthreads();
        if (tid == 0){
            float s = 0.f;
            #pragma unroll
            for (int w=0; w<8; w++) s += red[w];
            bdot_s = s;
        }
        // full hW = h @ Whc (K=512); 16 waves x 32 cols -> hWl
        int wn = wave * 32;
        int col16 = lane & 15;
        int khi = (lane >> 4) * 8;
        bool a_on = (col16 == 0);
        f32x4 acc[2];
        acc[0] = (f32x4){0.f,0.f,0.f,0.f};
        acc[1] = (f32x4){0.f,0.f,0.f,0.f};
        #pragma unroll
        for (int kk=0; kk<16; kk++){
            bf16x8 af = (bf16x8){0,0,0,0,0,0,0,0};
            if (a_on) af = *(const bf16x8*)&hls[kk*32 + khi];
            #pragma unroll
            for (int f=0;f<2;f++){
                bf16x8 bf = *(const bf16x8*)(WhcT + (size_t)(wn + f*16 + col16)*512 + kk*32 + khi);
                acc[f] = __builtin_amdgcn_mfma_f32_16x16x32_bf16(af, bf, acc[f], 0, 0, 0);
            }
        }
        if (lane < 16){
            #pragma unroll
            for (int f=0;f<2;f++) hWl[wn + f*16 + lane] = acc[f][0];
        }
    } else {
        if (tid < 512) hWl[tid] = hW0[(size_t)b*512 + tid];
        if (tid == 0) bdot_s = bdot0[b];
    }
    __syncthreads();
    // ---- phase E: e over own l-half (16 waves), own results also to LDS ----
    {
        float4 hw0v = *(float4*)&hWl[lane*8];
        float4 hw1v = *(float4*)&hWl[lane*8 + 4];
        const float* vp = v + lane*8;
        float4 v0 = *(const float4*)vp, v1 = *(const float4*)(vp+4);
        const int l0 = half*LH;
        for (int r = wave; r < LH; r += 16){
            int4 raw = *(const int4*)(wa + (((size_t)(b*L_ + l0 + r))<<9) + lane*8);
            const unsigned* u = (const unsigned*)&raw;
            float s;
            s  = fast_tanh(b2f_lo(u[0]) + hw0v.x)*v0.x;
            s += fast_tanh(b2f_hi(u[0]) + hw0v.y)*v0.y;
            s += fast_tanh(b2f_lo(u[1]) + hw0v.z)*v0.z;
            s += fast_tanh(b2f_hi(u[1]) + hw0v.w)*v0.w;
            s += fast_tanh(b2f_lo(u[2]) + hw1v.x)*v1.x;
            s += fast_tanh(b2f_hi(u[2]) + hw1v.y)*v1.y;
            s += fast_tanh(b2f_lo(u[3]) + hw1v.z)*v1.z;
            s += fast_tanh(b2f_hi(u[3]) + hw1v.w)*v1.w;
            #pragma unroll
            for (int off=32; off; off>>=1) s += __shfl_down(s, off);
            if (lane==0){ ebuf[b*L_ + l0 + r] = s; e_s[r] = s; }
        }
    }
    // ---- pair sync (the only one): e complete on both halves ----
    __syncthreads();
    if (tid == 0){
        __threadfence();
        atomicAdd(&ebar[b], 1u);
        const unsigned tgt = 2u*(unsigned)(t+1);
        while (__hip_atomic_load(&ebar[b], __ATOMIC_ACQUIRE, __HIP_MEMORY_SCOPE_AGENT) < tgt)
            __builtin_amdgcn_s_sleep(1);
    }
    __syncthreads();
    // ---- softmax over all 196: own half from LDS, sibling from global ----
    const int l0 = half*LH;
    float ev = -3.0e38f;
    if (tid < L_){
        int loc = tid - l0;
        ev = (loc >= 0 && loc < LH) ? e_s[loc] : ebuf[b*L_ + tid];
    }
    float wmax = ev;
    #pragma unroll
    for (int off=32; off; off>>=1) wmax = fmaxf(wmax, __shfl_down(wmax, off));
    if (lane==0) red[wave] = wmax;
    __syncthreads();
    float m = red[0];
    #pragma unroll
    for (int w=1; w<16; w++) m = fmaxf(m, red[w]);
    float pr = (tid < L_) ? __expf(ev - m) : 0.f;
    float wsum = pr;
    #pragma unroll
    for (int off=32; off; off>>=1) wsum += __shfl_down(wsum, off);
    if (lane==0) red[16+wave] = wsum;
    __syncthreads();
    float sum = red[16];
    #pragma unroll
    for (int w=1; w<16; w++) sum += red[16+w];
    float inv = 1.f / sum;
    if (tid < L_) al_s[tid] = pr*inv;
    if (tid >= l0 && tid < l0 + LH)
        __builtin_nontemporal_store(pr*inv, alphas_out + (size_t)b*TM1*L_ + (size_t)t*L_ + tid);
    __syncthreads();
    // ---- ctx: 256 d's per block, 4 d's per thread (uint2), 16-way l split ----
    {
        const int dg = tid & 63;
        const int lr = tid >> 6;            // 0..15
        const int d0 = half*256 + dg*4;
        const ushort_t* pa = a_b + (((size_t)(b*L_))<<9) + d0;
        float4 s = make_float4(0.f,0.f,0.f,0.f);
        for (int l = lr; l < L_; l += 16){
            uint2 av = *(const uint2*)(pa + ((size_t)l<<9));
            float al = al_s[l];
            s.x = fmaf(al, b2f_lo(av.x), s.x);
            s.y = fmaf(al, b2f_hi(av.x), s.y);
            s.z = fmaf(al, b2f_lo(av.y), s.z);
            s.w = fmaf(al, b2f_hi(av.y), s.w);
        }
        part4[lr][dg] = s;
        __syncthreads();
        if (tid < 64){
            float beta = sigmoidf_(bdot_s + beta_b[0]);
            float4 r = make_float4(0.f,0.f,0.f,0.f);
            #pragma unroll
            for (int q=0;q<16;q++){
                float4 pv = part4[q][tid];
                r.x += pv.x; r.y += pv.y; r.z += pv.z; r.w += pv.w;
            }
            unsigned lo = (unsigned)f2b(beta*r.x) | (((unsigned)f2b(beta*r.y))<<16);
            unsigned hi = (unsigned)f2b(beta*r.z) | (((unsigned)f2b(beta*r.w))<<16);
            uint2 pk; pk.x = lo; pk.y = hi;
            *(uint2*)(xcat + (size_t)b*KCAT + half*256 + tid*4) = pk;
        }
    }
}

// gates partials: grid (32, 8) x 256; tile M128 x N64, K-chunk 128
__global__ __launch_bounds__(256) void gates_k(const ushort_t* __restrict__ xcat,
                        const ushort_t* __restrict__ WcatT, float* __restrict__ gp){
    __shared__ ushort_t As[128*32];
    __shared__ ushort_t Bs[64*32];
    const int bn = blockIdx.x*64;
    const int ks = blockIdx.y;
    const int tid = threadIdx.x;
    const int lane = tid & 63, wave = tid >> 6;
    const int wm = wave*32;
    const int lrow = lane & 15;
    const int lk8 = (lane >> 4) * 8;
    f32x4 acc[2][4];
    #pragma unroll
    for (int i=0;i<2;i++)
        #pragma unroll
        for (int j=0;j<4;j++) acc[i][j] = (f32x4){0.f,0.f,0.f,0.f};

    for (int kk = 0; kk < 4; ++kk){
        int k0 = ks*128 + kk*32;
        int c0 = 2*tid;
        int r0 = c0 >> 2,  kq0 = (c0 & 3)*8;
        int r1 = (c0+1) >> 2, kq1 = ((c0+1) & 3)*8;
        int4 a0 = *(const int4*)(xcat + (size_t)r0*KCAT + k0 + kq0);
        int4 a1 = *(const int4*)(xcat + (size_t)r1*KCAT + k0 + kq1);
        int rb = tid >> 2, kqb = (tid & 3)*8;
        int4 b0 = *(const int4*)(WcatT + (size_t)(bn+rb)*KCAT + k0 + kqb);
        __syncthreads();
        *(int4*)&As[r0*32 + kq0] = a0;
        *(int4*)&As[r1*32 + kq1] = a1;
        *(int4*)&Bs[rb*32 + kqb] = b0;
        __syncthreads();
        bf16x8 af[2], bfr[4];
        #pragma unroll
        for (int i=0;i<2;i++) af[i] = *(bf16x8*)&As[(wm + i*16 + lrow)*32 + lk8];
        #pragma unroll
        for (int j=0;j<4;j++) bfr[j] = *(bf16x8*)&Bs[(j*16 + lrow)*32 + lk8];
        #pragma unroll
        for (int i=0;i<2;i++)
            #pragma unroll
            for (int j=0;j<4;j++)
                acc[i][j] = __builtin_amdgcn_mfma_f32_16x16x32_bf16(af[i], bfr[j], acc[i][j], 0, 0, 0);
    }
    const int rq = (lane >> 4) * 4;
    #pragma unroll
    for (int i=0;i<2;i++){
        #pragma unroll
        for (int j=0;j<4;j++){
            int gcol = bn + j*16 + lrow;
            #pragma unroll
            for (int q=0;q<4;q++){
                int grow = wm + i*16 + rq + q;
                gp[((size_t)(ks*B_ + grow))*G4H + gcol] = acc[i][j][q];
            }
        }
    }
}

// final lstm (h_19 -> Hall[18]); grid B x 512; reads cbuf2 parity 0 (after t=18)
__global__ __launch_bounds__(512) void lstmfin_k(const float* __restrict__ gp, const float* __restrict__ embWih,
                       const float* __restrict__ cbuf2, ushort_t* __restrict__ Hall){
    int b = blockIdx.x, j = threadIdx.x;
    const float* eb = embWih + ((size_t)(18*B_ + b))*G4H;
    float gi = eb[j], gf = eb[H_+j], gg = eb[2*H_+j], go = eb[3*H_+j];
    #pragma unroll
    for (int ks=0; ks<8; ks++){
        const float* g = gp + ((size_t)(ks*B_ + b))*G4H;
        gi += g[j]; gf += g[H_+j]; gg += g[2*H_+j]; go += g[3*H_+j];
    }
    float ig = sigmoidf_(gi), fg = sigmoidf_(gf);
    float g2 = fast_tanh(gg), og = sigmoidf_(go);
    float c = fg*cbuf2[b*H_+j] + ig*g2;
    float h = og*fast_tanh(c);
    Hall[((size_t)18*B_ + b)*H_ + j] = f2b(h);
}

extern "C" void kernel_launch(void* const* d_in, const int* in_sizes, int n_in,
                              void* d_out, int out_size, void* d_ws, size_t ws_size,
                              hipStream_t stream) {
    const float* a      = (const float*)d_in[0];
    const int*   caps   = (const int*)  d_in[1];
    const float* embW   = (const float*)d_in[3];
    const float* Wa     = (const float*)d_in[4];
    const float* Wh     = (const float*)d_in[5];
    const float* Wc     = (const float*)d_in[6];
    const float* v      = (const float*)d_in[7];
    const float* beta_W = (const float*)d_in[8];
    const float* beta_b = (const float*)d_in[9];
    const float* W_ih   = (const float*)d_in[10];
    const float* W_hh   = (const float*)d_in[11];
    const float* b_ih   = (const float*)d_in[12];
    const float* b_hh   = (const float*)d_in[13];
    const float* fc_W   = (const float*)d_in[14];
    const float* fc_b   = (const float*)d_in[15];
    const float* iWh    = (const float*)d_in[16];
    const float* ibh    = (const float*)d_in[17];
    const float* iWc    = (const float*)d_in[18];
    const float* ibc    = (const float*)d_in[19];

    float* out    = (float*)d_out;
    float* alphas = out + (size_t)ROWS*V_;

    // d_out scratch (dead before final logits GEMM overwrites it)
    char* ob = (char*)d_out;
    ushort_t* wa_b   = (ushort_t*)(ob);               // 25,690,112 B
    ushort_t* a_b    = (ushort_t*)(ob + 25690112);    // 25,690,112 B
    float*    embWih = (float*)   (ob + 51380224);    // 19,922,944 B

    // d_ws layout (byte offsets)
    char* wb = (char*)d_ws;
    float* mcp      = (float*)(wb);              // 1,048,576
    float* bdot0    = (float*)(wb + 1048576);    // 4096
    float* cbuf2    = (float*)(wb + 1052672);    // 524288 (2 parities)
    float* h0f      = (float*)(wb + 1576960);    // 262144
    float* hW0      = (float*)(wb + 1839104);    // 262144
    float* ebuf     = (float*)(wb + 2101248);    // 102400
    float* bias4h   = (float*)(wb + 2203648);    // 8192
    unsigned* bars  = (unsigned*)(wb + 2211840); // 4096: ebar[0..127]
    float* gp       = (float*)(wb + 2215936);    // 8388608
    ushort_t* xcat_b = (ushort_t*)(wb + 10604544);  // 262144
    ushort_t* xemb_b = (ushort_t*)(wb + 10866688);  // 1245184
    ushort_t* Hall   = (ushort_t*)(wb + 12111872);  // 2490368
    ushort_t* WaT    = (ushort_t*)(wb + 14602240);  // 524288
    ushort_t* WhcT   = (ushort_t*)(wb + 15126528);  // 524288
    ushort_t* WihT   = (ushort_t*)(wb + 15650816);  // 1048576
    ushort_t* WcatT  = (ushort_t*)(wb + 16699392);  // 4194304
    ushort_t* fcWT   = (ushort_t*)(wb + 20893696);  // 10354688 -> ends ~29.8MB

    // ---- prep (1 launch; mean blocks first so they overlap the transposes) ----
    PrepArgs P;
    P.j[0] = { Wa,   nullptr, WaT,  512, 512, 512,  0,   512,  16, 256 };
    P.j[1] = { Wh,   Wc,      WhcT, 512, 512, 512,  0,   512,  16, 256 };
    P.j[2] = { W_ih, nullptr, WihT, G4H, 256, G4H,  0,   256,  64, 512 };
    P.j[3] = { W_ih + (size_t)E_*G4H, nullptr, WcatT, G4H, 512, G4H, 0,   KCAT, 64, 1024 };
    P.j[4] = { W_hh, nullptr, WcatT, G4H, 512, G4H,  512, KCAT, 64, 1024 };
    P.j[5] = { fc_W, nullptr, fcWT, V_,  512, V_,   0,   512,  316, 5056 };
    P.a = a; P.a_b = a_b; P.mcp = mcp;
    P.b_ih = b_ih; P.b_hh = b_hh; P.bias4h = bias4h; P.bars = bars;
    P.caps = caps; P.embW = embW; P.xemb = xemb_b;
    prep_all_k<<<8993, 256, 0, stream>>>(P);

    gemm64t2<<<dim3(8,2,2), 256, 0, stream>>>(mcp, D_, iWh, iWc, H_, h0f, cbuf2, H_, ibh, ibc);
    hw0cvt_k<<<B_, 512, 0, stream>>>(h0f, WhcT, beta_W, xcat_b, hW0, bdot0);

    // wa_b + embWih in one dispatch
    GJob g0 = { a_b,    512, WaT,  512, wa_b,   512, 512,  512, nullptr, 1, 4,  784 };
    GJob g1 = { xemb_b, 256, WihT, 256, embWih, G4H, G4H,  256, bias4h,  0, 16, 304 };
    gemm_dual_k<<<1088, 256, 0, stream>>>(g0, g1);

    // ---- loop: 2 kernels/step, single pair-sync inside mega2 ----
    for (int t = 0; t < TM1; ++t){
        mega2_k<<<dim3(B_,2), 1024, 0, stream>>>(wa_b, a_b, v, beta_W, beta_b, WhcT,
                                                 gp, embWih, cbuf2, hW0, bdot0, xcat_b, Hall,
                                                 alphas, ebuf, bars, t);
        gates_k<<<dim3(32,8), 256, 0, stream>>>(xcat_b, WcatT, gp);
    }
    lstmfin_k<<<B_, 512, 0, stream>>>(gp, embWih, cbuf2, Hall);

    // logits = Hall @ fc_W + fc_b   (2432 x 10000 x 512), BK=64 swizzled
    gemm_logits_k<<<dim3(1520), 256, 0, stream>>>(Hall, H_, fcWT, H_, out, V_, V_, H_, fc_b);
}